// Round 1
// baseline (8896.107 us; speedup 1.0000x reference)
//
#include <hip/hip_runtime.h>
#include <hip/hip_bf16.h>

// ---------------- constants ----------------
#define BB 32
#define TT 128
#define DD 512
#define NW 2000
#define NCC 200
#define SS 8
#define LL 4
#define HH 8
#define FF 2048
#define HD 64

// ---------------- generic tiled GEMM ----------------
// C[M,N] = act( accum?C:0 + alpha * A[M,K] @ (TRANSB ? B[N,K]^T : B[K,N]) + bias )
// batch z: off = (z/batchH)*s1 + (z%batchH)*s2 for A,B,C independently.
template<int TRANSB, int ACT, int ACCUM>
__global__ __launch_bounds__(256) void gemm_k(
    const float* __restrict__ A, int lda, long sA1, long sA2,
    const float* __restrict__ B, int ldb, long sB1, long sB2,
    float* __restrict__ C, int ldc, long sC1, long sC2,
    const float* __restrict__ bias,
    int M, int N, int K, float alpha, int batchH)
{
    __shared__ float As[16][68];
    __shared__ float Bs[16][68];
    int z = blockIdx.z;
    int zb = z / batchH, zh = z % batchH;
    A += zb * sA1 + zh * sA2;
    B += zb * sB1 + zh * sB2;
    C += zb * sC1 + zh * sC2;
    int m0 = blockIdx.y * 64, n0 = blockIdx.x * 64;
    int tid = threadIdx.x;
    int tr = tid / 16, tc = tid % 16;
    float acc[4][4] = {};
    for (int k0 = 0; k0 < K; k0 += 16) {
        {   // A tile: 64 (m) x 16 (k)
            int ar = tid / 4;
            int ac = (tid % 4) * 4;
            int gm = m0 + ar;
            #pragma unroll
            for (int i = 0; i < 4; i++) {
                int gk = k0 + ac + i;
                As[ac + i][ar] = (gm < M && gk < K) ? A[(long)gm * lda + gk] : 0.f;
            }
        }
        if (!TRANSB) { // B tile: 16 (k) x 64 (n)
            int br = tid / 16;
            int bc = (tid % 16) * 4;
            int gk = k0 + br;
            #pragma unroll
            for (int i = 0; i < 4; i++) {
                int gn = n0 + bc + i;
                Bs[br][bc + i] = (gk < K && gn < N) ? B[(long)gk * ldb + gn] : 0.f;
            }
        } else {       // B is (N x K); Bs[kk][n] = B[n][k]
            int bn = tid / 4;
            int bk = (tid % 4) * 4;
            int gn = n0 + bn;
            #pragma unroll
            for (int i = 0; i < 4; i++) {
                int gk = k0 + bk + i;
                Bs[bk + i][bn] = (gn < N && gk < K) ? B[(long)gn * ldb + gk] : 0.f;
            }
        }
        __syncthreads();
        #pragma unroll
        for (int kk = 0; kk < 16; kk++) {
            float a[4], b[4];
            #pragma unroll
            for (int i = 0; i < 4; i++) a[i] = As[kk][tr * 4 + i];
            #pragma unroll
            for (int i = 0; i < 4; i++) b[i] = Bs[kk][tc * 4 + i];
            #pragma unroll
            for (int i = 0; i < 4; i++)
                #pragma unroll
                for (int j = 0; j < 4; j++)
                    acc[i][j] += a[i] * b[j];
        }
        __syncthreads();
    }
    #pragma unroll
    for (int i = 0; i < 4; i++) {
        int gm = m0 + tr * 4 + i;
        if (gm >= M) continue;
        #pragma unroll
        for (int j = 0; j < 4; j++) {
            int gn = n0 + tc * 4 + j;
            if (gn >= N) continue;
            float v = acc[i][j] * alpha;
            long ci = (long)gm * ldc + gn;
            if (ACCUM) v += C[ci];
            if (bias) v += bias[gn];
            if (ACT == 1) v = fmaxf(v, 0.f);
            C[ci] = v;
        }
    }
}

// ---------------- elementwise ----------------
__global__ void addpos_k(const float* __restrict__ a, const float* __restrict__ pos,
                         float* __restrict__ o, long n, long pmod) {
    for (long i = blockIdx.x * (long)blockDim.x + threadIdx.x; i < n;
         i += (long)gridDim.x * blockDim.x)
        o[i] = a[i] + pos[i % pmod];
}
__global__ void add_k(const float* __restrict__ a, const float* __restrict__ b,
                      float* __restrict__ o, long n) {
    for (long i = blockIdx.x * (long)blockDim.x + threadIdx.x; i < n;
         i += (long)gridDim.x * blockDim.x)
        o[i] = a[i] + b[i];
}
__global__ void zero_k(float* __restrict__ p, long n) {
    for (long i = blockIdx.x * (long)blockDim.x + threadIdx.x; i < n;
         i += (long)gridDim.x * blockDim.x)
        p[i] = 0.f;
}
__global__ void sentinel_k(float* p) { p[0] = 1e9f; }

// ---------------- residual + layernorm (in-place on x) ----------------
__global__ __launch_bounds__(256) void ln_res_k(float* __restrict__ x,
                                                const float* __restrict__ z,
                                                const float* __restrict__ g,
                                                const float* __restrict__ b) {
    long row = blockIdx.x;
    float* px = x + row * DD;
    const float* pz = z + row * DD;
    int t = threadIdx.x;
    float v0 = px[t] + pz[t];
    float v1 = px[t + 256] + pz[t + 256];
    float s = v0 + v1, sq = v0 * v0 + v1 * v1;
    for (int o = 32; o > 0; o >>= 1) {
        s += __shfl_xor(s, o, 64);
        sq += __shfl_xor(sq, o, 64);
    }
    __shared__ float ss[4], sqq[4];
    int wave = t >> 6, lane = t & 63;
    if (lane == 0) { ss[wave] = s; sqq[wave] = sq; }
    __syncthreads();
    s = ss[0] + ss[1] + ss[2] + ss[3];
    sq = sqq[0] + sqq[1] + sqq[2] + sqq[3];
    float mean = s * (1.f / DD);
    float var = sq * (1.f / DD) - mean * mean;
    float rstd = 1.f / sqrtf(var + 1e-5f);
    px[t] = (v0 - mean) * rstd * g[t] + b[t];
    px[t + 256] = (v1 - mean) * rstd * g[t + 256] + b[t + 256];
}

// ---------------- softmax over rows of length 128 ----------------
__global__ __launch_bounds__(256) void softmax128_k(float* __restrict__ s, long nrows) {
    int wave = threadIdx.x >> 6, lane = threadIdx.x & 63;
    long row = (long)blockIdx.x * 4 + wave;
    if (row >= nrows) return;
    float* p = s + row * 128;
    float a0 = p[lane], a1 = p[lane + 64];
    float m = fmaxf(a0, a1);
    for (int o = 32; o > 0; o >>= 1) m = fmaxf(m, __shfl_xor(m, o, 64));
    float e0 = expf(a0 - m), e1 = expf(a1 - m);
    float sum = e0 + e1;
    for (int o = 32; o > 0; o >>= 1) sum += __shfl_xor(sum, o, 64);
    float inv = 1.f / sum;
    p[lane] = e0 * inv;
    p[lane + 64] = e1 * inv;
}

// ---------------- fused cross-attention (per (b, concept)) ----------------
__global__ __launch_bounds__(64) void cross_attn_k(const float* __restrict__ Qp,
                                                   const float* __restrict__ Kp,
                                                   const float* __restrict__ Vp,
                                                   float* __restrict__ updc,
                                                   int n0, int chunk) {
    int j = blockIdx.x, b = blockIdx.y;
    int n = n0 + j;
    int lane = threadIdx.x;
    __shared__ float qs[DD];
    __shared__ float aw[TT];
    #pragma unroll
    for (int i = 0; i < 8; i++) qs[i * 64 + lane] = Qp[(long)n * DD + i * 64 + lane];
    __syncthreads();
    const float* kb = Kp + (long)b * TT * DD;
    const float* vb = Vp + (long)b * TT * DD;
    float* ub = updc + ((long)b * chunk + j) * DD;
    for (int h = 0; h < HH; h++) {
        const float* q = qs + h * HD;
        const float* k0 = kb + h * HD;
        float s0 = 0.f, s1 = 0.f;
        #pragma unroll 8
        for (int d = 0; d < HD; d++) {
            float qd = q[d];
            s0 += qd * k0[(long)lane * DD + d];
            s1 += qd * k0[(long)(lane + 64) * DD + d];
        }
        s0 *= 0.125f; s1 *= 0.125f;
        float m = fmaxf(s0, s1);
        for (int o = 32; o > 0; o >>= 1) m = fmaxf(m, __shfl_xor(m, o, 64));
        float e0 = expf(s0 - m), e1 = expf(s1 - m);
        float sum = e0 + e1;
        for (int o = 32; o > 0; o >>= 1) sum += __shfl_xor(sum, o, 64);
        float inv = 1.f / sum;
        aw[lane] = e0 * inv;
        aw[lane + 64] = e1 * inv;
        __syncthreads();
        float acc = 0.f;
        const float* vcol = vb + h * HD + lane;
        #pragma unroll 8
        for (int t = 0; t < TT; t++) acc += aw[t] * vcol[(long)t * DD];
        ub[h * HD + lane] = acc;
        __syncthreads();
    }
}

// ---------------- conv helpers ----------------
// pad feats_proj (B,128,2000) -> (B,130,2000) interior rows 1..128
__global__ void pad_copy_k(const float* __restrict__ fp, float* __restrict__ fpp) {
    long total = (long)BB * TT * NW;
    for (long i = blockIdx.x * (long)blockDim.x + threadIdx.x; i < total;
         i += (long)gridDim.x * blockDim.x) {
        long ci = i % NW;
        long r = i / NW;
        long t = r % TT;
        long b = r / TT;
        fpp[(b * 130 + t + 1) * NW + ci] = fp[i];
    }
}
// w[co][ci][kt] -> wk[kt][co][ci]
__global__ void repack_k(const float* __restrict__ w, float* __restrict__ wk,
                         int CO, int CI) {
    long total = (long)CO * CI * 3;
    for (long i = blockIdx.x * (long)blockDim.x + threadIdx.x; i < total;
         i += (long)gridDim.x * blockDim.x) {
        long kt = i % 3;
        long r = i / 3;
        long ci = r % CI;
        long co = r / CI;
        wk[kt * (long)CO * CI + co * CI + ci] = w[i];
    }
}
// conv5 (128 -> 1) + sigmoid, writes frames_cls
__global__ __launch_bounds__(128) void conv5_k(const float* __restrict__ h4,
                                               const float* __restrict__ w,
                                               const float* __restrict__ bias,
                                               float* __restrict__ out) {
    int b = blockIdx.x, t = threadIdx.x;
    __shared__ float ws[384];
    ws[t] = w[t];
    ws[t + 128] = w[t + 128];
    ws[t + 256] = w[t + 256];
    __syncthreads();
    const float* hb = h4 + (long)b * 128 * 130;
    float acc = bias[0];
    for (int ci = 0; ci < 128; ci++) {
        const float* r = hb + ci * 130 + t;
        float w0 = ws[ci * 3], w1 = ws[ci * 3 + 1], w2 = ws[ci * 3 + 2];
        acc += w0 * r[0] + w1 * r[1] + w2 * r[2];
    }
    out[b * TT + t] = 1.f / (1.f + expf(-acc));
}

// ---------------- masked segment softmax pooling ----------------
__global__ __launch_bounds__(128) void seg_pool_k(const float* __restrict__ weights,
                                                  const int* __restrict__ steds,
                                                  const float* __restrict__ vid,
                                                  float* __restrict__ segf) {
    int b = blockIdx.y, sidx = blockIdx.x;
    int st = steds[(b * SS + sidx) * 2];
    int ed = steds[(b * SS + sidx) * 2 + 1];
    int t = threadIdx.x;
    float w = (t >= st && t <= ed) ? weights[b * TT + t] : -1e30f;
    __shared__ float red[2];
    __shared__ float aw[TT];
    int wave = t >> 6, lane = t & 63;
    float m = w;
    for (int o = 32; o > 0; o >>= 1) m = fmaxf(m, __shfl_xor(m, o, 64));
    if (lane == 0) red[wave] = m;
    __syncthreads();
    m = fmaxf(red[0], red[1]);
    float e = expf(w - m);
    float sum = e;
    for (int o = 32; o > 0; o >>= 1) sum += __shfl_xor(sum, o, 64);
    __syncthreads();
    if (lane == 0) red[wave] = sum;
    __syncthreads();
    sum = red[0] + red[1];
    aw[t] = e / sum;
    __syncthreads();
    #pragma unroll
    for (int i = 0; i < 4; i++) {
        int d = t + i * 128;
        float acc = 0.f;
        for (int tt = 0; tt < TT; tt++)
            acc += aw[tt] * vid[((long)b * TT + tt) * DD + d];
        segf[((long)b * SS + sidx) * DD + d] = acc;
    }
}

// ---------------- host-side GEMM dispatch ----------------
static void launch_gemm(int transb, int act, int accum,
                        const float* A, int lda, long sA1, long sA2,
                        const float* B, int ldb, long sB1, long sB2,
                        float* C, int ldc, long sC1, long sC2,
                        const float* bias, int M, int N, int K, float alpha,
                        int batchH, int Z, hipStream_t st) {
    dim3 grid((N + 63) / 64, (M + 63) / 64, Z), blk(256);
#define GO(TB, A_, AC)                                                     \
    gemm_k<TB, A_, AC><<<grid, blk, 0, st>>>(A, lda, sA1, sA2, B, ldb, sB1, \
                                             sB2, C, ldc, sC1, sC2, bias, M, \
                                             N, K, alpha, batchH)
    if (transb) {
        if (act) { if (accum) GO(1, 1, 1); else GO(1, 1, 0); }
        else     { if (accum) GO(1, 0, 1); else GO(1, 0, 0); }
    } else {
        if (act) { if (accum) GO(0, 1, 1); else GO(0, 1, 0); }
        else     { if (accum) GO(0, 0, 1); else GO(0, 0, 0); }
    }
#undef GO
}

extern "C" void kernel_launch(void* const* d_in, const int* in_sizes, int n_in,
                              void* d_out, int out_size, void* d_ws, size_t ws_size,
                              hipStream_t stream) {
    const float* vid = (const float*)d_in[0];
    const float* actn_feats = (const float*)d_in[2];
    const float* actn_concepts = (const float*)d_in[3];
    const float* pos = (const float*)d_in[4];
    const float* Wq = (const float*)d_in[5];
    const float* bq = (const float*)d_in[6];
    const float* Wk = (const float*)d_in[7];
    const float* bk = (const float*)d_in[8];
    const float* Wv = (const float*)d_in[9];
    const float* bv = (const float*)d_in[10];
    const float* Wo = (const float*)d_in[11];
    const float* bo = (const float*)d_in[12];
    const float* W1 = (const float*)d_in[13];
    const float* b1 = (const float*)d_in[14];
    const float* W2 = (const float*)d_in[15];
    const float* b2 = (const float*)d_in[16];
    const float* g1 = (const float*)d_in[17];
    const float* bb1 = (const float*)d_in[18];
    const float* g2 = (const float*)d_in[19];
    const float* bb2 = (const float*)d_in[20];
    const float* pqW = (const float*)d_in[21];
    const float* pqb = (const float*)d_in[22];
    const float* pkW = (const float*)d_in[23];
    const float* pkb = (const float*)d_in[24];
    const float* pvW = (const float*)d_in[25];
    const float* pvb = (const float*)d_in[26];
    const float* c1w = (const float*)d_in[27];
    const float* c1b = (const float*)d_in[28];
    const float* c2w = (const float*)d_in[29];
    const float* c2b = (const float*)d_in[30];
    const float* c3w = (const float*)d_in[31];
    const float* c3b = (const float*)d_in[32];
    const float* c4w = (const float*)d_in[33];
    const float* c4b = (const float*)d_in[34];
    const float* c5w = (const float*)d_in[35];
    const float* c5b = (const float*)d_in[36];
    const int* steds = (const int*)d_in[37];

    float* out = (float*)d_out;
    float* fc_out = out;            // 32*128
    float* al_out = out + 4096;     // 32*8*200
    float* fp_out = out + 55296;    // 32*128*2000

    float* ws = (float*)d_ws;
    // arena offsets (floats)
    const long OF_VPROJ = 0;
    const long OF_X     = 2097152;
    const long OF_Q     = 4194304;   // also Qp
    const long OF_K     = 6291456;   // also Kp
    const long OF_V     = 8388608;   // also Vp
    const long OF_AO    = 10485760;
    const long OF_S     = 12582912;  // scores 4,194,304
    const long OF_FFH   = 16777216;  // ffh 8,388,608
    const long OF_UPD   = 10485760;  // upd chunk 8,192,000 (phase B)
    // conv phase (everything above dead)
    const long OF_FPP   = 0;         // 8,320,000
    const long OF_H1    = 8320000;   // 4,259,840
    const long OF_H2    = 12579840;  // 2,129,920
    const long OF_H3    = 14709760;  // 1,064,960
    const long OF_H4    = 15774720;  // 532,480
    const long OF_SEGF  = 16307200;  // 131,072
    const long OF_WK1   = 16438272;  // 6,144,000
    const long OF_WK2   = 22582272;  // 1,572,864
    const long OF_WK3   = 24155136;  // 393,216
    const long OF_WK4   = 24548352;  // 98,304
    const long NEED     = 25165824;  // floats (~96 MB)
    if (ws_size < (size_t)NEED * 4) {
        sentinel_k<<<1, 1, 0, stream>>>(fc_out);
        return;
    }

    float* xb   = ws + OF_X;
    float* qb   = ws + OF_Q;
    float* kb   = ws + OF_K;
    float* vb   = ws + OF_V;
    float* aob  = ws + OF_AO;
    float* sb   = ws + OF_S;
    float* ffh  = ws + OF_FFH;
    float* vpr  = ws + OF_VPROJ;

    const long nBTD = (long)BB * TT * DD;  // 2,097,152

    // x = vid + pos
    addpos_k<<<2048, 256, 0, stream>>>(vid, pos, xb, nBTD, (long)TT * DD);

    // ---- transformer layers ----
    for (int l = 0; l < LL; l++) {
        const float* Wq_l = Wq + (long)l * DD * DD;
        const float* Wk_l = Wk + (long)l * DD * DD;
        const float* Wv_l = Wv + (long)l * DD * DD;
        const float* Wo_l = Wo + (long)l * DD * DD;
        const float* bq_l = bq + (long)l * DD;
        const float* bk_l = bk + (long)l * DD;
        const float* bv_l = bv + (long)l * DD;
        const float* bo_l = bo + (long)l * DD;
        const float* W1_l = W1 + (long)l * DD * FF;
        const float* b1_l = b1 + (long)l * FF;
        const float* W2_l = W2 + (long)l * FF * DD;
        const float* b2_l = b2 + (long)l * DD;

        // q,k,v
        launch_gemm(0, 0, 0, xb, DD, 0, 0, Wq_l, DD, 0, 0, qb, DD, 0, 0, bq_l,
                    BB * TT, DD, DD, 1.f, 1, 1, stream);
        launch_gemm(0, 0, 0, xb, DD, 0, 0, Wk_l, DD, 0, 0, kb, DD, 0, 0, bk_l,
                    BB * TT, DD, DD, 1.f, 1, 1, stream);
        launch_gemm(0, 0, 0, xb, DD, 0, 0, Wv_l, DD, 0, 0, vb, DD, 0, 0, bv_l,
                    BB * TT, DD, DD, 1.f, 1, 1, stream);
        // scores[b,h] = q[b,:,h] @ k[b,:,h]^T / 8
        launch_gemm(1, 0, 0, qb, DD, (long)TT * DD, HD,
                    kb, DD, (long)TT * DD, HD,
                    sb, TT, (long)HH * TT * TT, (long)TT * TT,
                    nullptr, TT, TT, HD, 0.125f, HH, BB * HH, stream);
        softmax128_k<<<(BB * HH * TT) / 4, 256, 0, stream>>>(sb, (long)BB * HH * TT);
        // ao[b,:,h] = scores[b,h] @ v[b,:,h]
        launch_gemm(0, 0, 0, sb, TT, (long)HH * TT * TT, (long)TT * TT,
                    vb, DD, (long)TT * DD, HD,
                    aob, DD, (long)TT * DD, HD,
                    nullptr, TT, HD, TT, 1.f, HH, BB * HH, stream);
        // out proj -> qb (scratch)
        launch_gemm(0, 0, 0, aob, DD, 0, 0, Wo_l, DD, 0, 0, qb, DD, 0, 0, bo_l,
                    BB * TT, DD, DD, 1.f, 1, 1, stream);
        // x = LN(x + qb)
        ln_res_k<<<BB * TT, 256, 0, stream>>>(xb, qb, g1 + (long)l * DD, bb1 + (long)l * DD);
        // ff
        launch_gemm(0, 1, 0, xb, DD, 0, 0, W1_l, FF, 0, 0, ffh, FF, 0, 0, b1_l,
                    BB * TT, FF, DD, 1.f, 1, 1, stream);
        launch_gemm(0, 0, 0, ffh, FF, 0, 0, W2_l, DD, 0, 0, qb, DD, 0, 0, b2_l,
                    BB * TT, DD, FF, 1.f, 1, 1, stream);
        ln_res_k<<<BB * TT, 256, 0, stream>>>(xb, qb, g2 + (long)l * DD, bb2 + (long)l * DD);
    }

    // vproj = vid + x
    add_k<<<2048, 256, 0, stream>>>(vid, xb, vpr, nBTD);

    // projections: Qp (2000x512), Kp, Vp
    launch_gemm(0, 0, 0, actn_concepts, DD, 0, 0, pqW, DD, 0, 0, qb, DD, 0, 0,
                pqb, NW, DD, DD, 1.f, 1, 1, stream);
    launch_gemm(0, 0, 0, vpr, DD, 0, 0, pkW, DD, 0, 0, kb, DD, 0, 0, pkb,
                BB * TT, DD, DD, 1.f, 1, 1, stream);
    launch_gemm(0, 0, 0, vpr, DD, 0, 0, pvW, DD, 0, 0, vb, DD, 0, 0, pvb,
                BB * TT, DD, DD, 1.f, 1, 1, stream);

    // cross-attn + feats_proj, chunked over NW
    const int CHUNK = 500;
    float* updc = ws + OF_UPD;
    for (int c = 0; c < NW / CHUNK; c++) {
        int n0 = c * CHUNK;
        cross_attn_k<<<dim3(CHUNK, BB), 64, 0, stream>>>(qb, kb, vb, updc, n0, CHUNK);
        // fp[b, :, n0:n0+CHUNK] = vproj[b] @ updc[b]^T
        launch_gemm(1, 0, 0, vpr, DD, (long)TT * DD, 0,
                    updc, DD, (long)CHUNK * DD, 0,
                    fp_out + n0, NW, (long)TT * NW, 0,
                    nullptr, TT, CHUNK, DD, 1.f, 1, BB, stream);
    }

    // ---- conv tower ----
    float* wk1 = ws + OF_WK1;
    float* wk2 = ws + OF_WK2;
    float* wk3 = ws + OF_WK3;
    float* wk4 = ws + OF_WK4;
    repack_k<<<1024, 256, 0, stream>>>(c1w, wk1, 1024, NW);
    repack_k<<<512, 256, 0, stream>>>(c2w, wk2, 512, 1024);
    repack_k<<<256, 256, 0, stream>>>(c3w, wk3, 256, 512);
    repack_k<<<128, 256, 0, stream>>>(c4w, wk4, 128, 256);
    zero_k<<<4096, 256, 0, stream>>>(ws, OF_WK1);  // conv buffers + pads
    float* fpp = ws + OF_FPP;
    float* h1 = ws + OF_H1;
    float* h2 = ws + OF_H2;
    float* h3 = ws + OF_H3;
    float* h4 = ws + OF_H4;
    pad_copy_k<<<2048, 256, 0, stream>>>(fp_out, fpp);

    // conv1: TRANSB (input is (t, ci) row-major), co=1024, ci=2000
    for (int kt = 0; kt < 3; kt++) {
        launch_gemm(1, kt == 2 ? 1 : 0, kt > 0 ? 1 : 0,
                    wk1 + (long)kt * 1024 * NW, NW, 0, 0,
                    fpp + (long)kt * NW, NW, (long)130 * NW, 0,
                    h1 + 1, 130, (long)1024 * 130, 0,
                    kt == 0 ? c1b : nullptr, 1024, TT, NW, 1.f, 1, BB, stream);
    }
    // conv2..4: non-TRANSB (input is (ci, t) row-major)
    for (int kt = 0; kt < 3; kt++) {
        launch_gemm(0, kt == 2 ? 1 : 0, kt > 0 ? 1 : 0,
                    wk2 + (long)kt * 512 * 1024, 1024, 0, 0,
                    h1 + kt, 130, (long)1024 * 130, 0,
                    h2 + 1, 130, (long)512 * 130, 0,
                    kt == 0 ? c2b : nullptr, 512, TT, 1024, 1.f, 1, BB, stream);
    }
    for (int kt = 0; kt < 3; kt++) {
        launch_gemm(0, kt == 2 ? 1 : 0, kt > 0 ? 1 : 0,
                    wk3 + (long)kt * 256 * 512, 512, 0, 0,
                    h2 + kt, 130, (long)512 * 130, 0,
                    h3 + 1, 130, (long)256 * 130, 0,
                    kt == 0 ? c3b : nullptr, 256, TT, 512, 1.f, 1, BB, stream);
    }
    for (int kt = 0; kt < 3; kt++) {
        launch_gemm(0, kt == 2 ? 1 : 0, kt > 0 ? 1 : 0,
                    wk4 + (long)kt * 128 * 256, 256, 0, 0,
                    h3 + kt, 130, (long)256 * 130, 0,
                    h4 + 1, 130, (long)128 * 130, 0,
                    kt == 0 ? c4b : nullptr, 128, TT, 256, 1.f, 1, BB, stream);
    }
    conv5_k<<<BB, 128, 0, stream>>>(h4, c5w, c5b, fc_out);

    // ---- segment pooling + logits ----
    float* segf = ws + OF_SEGF;
    seg_pool_k<<<dim3(SS, BB), 128, 0, stream>>>(fc_out, steds, vid, segf);
    launch_gemm(1, 0, 0, segf, DD, 0, 0, actn_feats, DD, 0, 0, al_out, NCC, 0, 0,
                nullptr, BB * SS, NCC, DD, 1.f, 1, 1, stream);
}

// Round 2
// 2325.351 us; speedup vs baseline: 3.8257x; 3.8257x over previous
//
#include <hip/hip_runtime.h>
#include <hip/hip_bf16.h>

// ---------------- constants ----------------
#define BB 32
#define TT 128
#define DD 512
#define NW 2000
#define NCC 200
#define SS 8
#define LL 4
#define HH 8
#define FF 2048
#define HD 64

typedef unsigned short ushort_t;
typedef __attribute__((ext_vector_type(8))) short bhalf8;
typedef __attribute__((ext_vector_type(4))) float floatx4;

__device__ inline ushort_t f2b(float x) {
    union { float f; unsigned int u; } v; v.f = x;
    unsigned int r = (v.u + 0x7FFFu + ((v.u >> 16) & 1u)) >> 16;
    return (ushort_t)r;
}
__device__ inline float b2f(ushort_t u) {
    union { unsigned int u; float f; } v; v.u = ((unsigned int)u) << 16;
    return v.f;
}

// ================= bf16 MFMA GEMM =================
// C[M,N] = act( alpha * sum_tap A[M,K] @ B[N,K]^T + bias )
// A: bf16 M x K row-major (lda). B: bf16 N x K row-major (ldb) ("B^T" storage).
// batch z: zb=z/batchH, zh=z%batchH; offsets sA1*zb+sA2*zh etc (element units).
// taps: accumulate over tap with A += tap*tapA, B += tap*tapB (for conv1d).
template<int ACT, int OUTBF>
__global__ __launch_bounds__(256) void bgemm_k(
    const ushort_t* __restrict__ A, int lda, long sA1, long sA2,
    const ushort_t* __restrict__ B, int ldb, long sB1, long sB2,
    void* __restrict__ Cv, int ldc, long sC1, long sC2,
    const float* __restrict__ bias,
    int M, int N, int K, float alpha, int batchH,
    int taps, long tapA, long tapB)
{
    __shared__ __align__(16) ushort_t As[128][72];
    __shared__ __align__(16) ushort_t Bs[128][72];
    int z = blockIdx.z;
    int zb = z / batchH, zh = z % batchH;
    A += zb * sA1 + zh * sA2;
    B += zb * sB1 + zh * sB2;
    long cOff = (long)zb * sC1 + (long)zh * sC2;
    int m0 = blockIdx.y * 128, n0 = blockIdx.x * 128;
    int tid = threadIdx.x;
    int wid = tid >> 6, lane = tid & 63;
    int wr = wid >> 1, wc = wid & 1;
    int lr = lane & 15, lg = lane >> 4;

    floatx4 acc[4][4];
    #pragma unroll
    for (int i = 0; i < 4; i++)
        #pragma unroll
        for (int j = 0; j < 4; j++)
            acc[i][j] = (floatx4){0.f, 0.f, 0.f, 0.f};

    for (int tap = 0; tap < taps; tap++) {
        const ushort_t* At = A + tap * tapA;
        const ushort_t* Bt = B + tap * tapB;
        for (int k0 = 0; k0 < K; k0 += 64) {
            #pragma unroll
            for (int i = 0; i < 4; i++) {
                int c = i * 256 + tid;
                int row = c >> 3;
                int kc = (c & 7) * 8;
                int gk = k0 + kc;
                uint4 va = {0, 0, 0, 0}, vb = {0, 0, 0, 0};
                int gm = m0 + row;
                if (gm < M && gk < K)  // K,lda multiples of 8 -> full chunk valid
                    va = *(const uint4*)(At + (long)gm * lda + gk);
                int gn = n0 + row;
                if (gn < N && gk < K)
                    vb = *(const uint4*)(Bt + (long)gn * ldb + gk);
                *(uint4*)&As[row][kc] = va;
                *(uint4*)&Bs[row][kc] = vb;
            }
            __syncthreads();
            #pragma unroll
            for (int kk = 0; kk < 2; kk++) {
                bhalf8 a_[4], b_[4];
                #pragma unroll
                for (int i = 0; i < 4; i++)
                    a_[i] = *(const bhalf8*)&As[wr * 64 + i * 16 + lr][kk * 32 + lg * 8];
                #pragma unroll
                for (int j = 0; j < 4; j++)
                    b_[j] = *(const bhalf8*)&Bs[wc * 64 + j * 16 + lr][kk * 32 + lg * 8];
                #pragma unroll
                for (int i = 0; i < 4; i++)
                    #pragma unroll
                    for (int j = 0; j < 4; j++)
                        acc[i][j] = __builtin_amdgcn_mfma_f32_16x16x32_bf16(
                            a_[i], b_[j], acc[i][j], 0, 0, 0);
            }
            __syncthreads();
        }
    }
    // epilogue: C/D layout col=lane&15, row=(lane>>4)*4+reg  [m89-verified]
    #pragma unroll
    for (int i = 0; i < 4; i++) {
        int gm_base = m0 + wr * 64 + i * 16 + lg * 4;
        #pragma unroll
        for (int j = 0; j < 4; j++) {
            int gn = n0 + wc * 64 + j * 16 + lr;
            if (gn >= N) continue;
            float bv = bias ? bias[gn] : 0.f;
            #pragma unroll
            for (int r = 0; r < 4; r++) {
                int gm = gm_base + r;
                if (gm >= M) continue;
                float v = acc[i][j][r] * alpha + bv;
                if (ACT == 1) v = fmaxf(v, 0.f);
                long idx = cOff + (long)gm * ldc + gn;
                if (OUTBF) ((ushort_t*)Cv)[idx] = f2b(v);
                else       ((float*)Cv)[idx] = v;
            }
        }
    }
}

static void launch_bgemm(int act, int outbf,
                         const ushort_t* A, int lda, long sA1, long sA2,
                         const ushort_t* B, int ldb, long sB1, long sB2,
                         void* C, int ldc, long sC1, long sC2,
                         const float* bias, int M, int N, int K, float alpha,
                         int batchH, int Z, int taps, long tapA, long tapB,
                         hipStream_t st) {
    dim3 grid((N + 127) / 128, (M + 127) / 128, Z), blk(256);
#define BG(A_, O_) bgemm_k<A_, O_><<<grid, blk, 0, st>>>(A, lda, sA1, sA2, B, ldb, sB1, sB2, C, ldc, sC1, sC2, bias, M, N, K, alpha, batchH, taps, tapA, tapB)
    if (act) { if (outbf) BG(1, 1); else BG(1, 0); }
    else     { if (outbf) BG(0, 1); else BG(0, 0); }
#undef BG
}

// ================= fp32 tiled GEMM (small/sensitive ops) =================
template<int TRANSB, int ACT, int ACCUM>
__global__ __launch_bounds__(256) void gemm_k(
    const float* __restrict__ A, int lda, long sA1, long sA2,
    const float* __restrict__ B, int ldb, long sB1, long sB2,
    float* __restrict__ C, int ldc, long sC1, long sC2,
    const float* __restrict__ bias,
    int M, int N, int K, float alpha, int batchH)
{
    __shared__ float As[16][68];
    __shared__ float Bs[16][68];
    int z = blockIdx.z;
    int zb = z / batchH, zh = z % batchH;
    A += zb * sA1 + zh * sA2;
    B += zb * sB1 + zh * sB2;
    C += zb * sC1 + zh * sC2;
    int m0 = blockIdx.y * 64, n0 = blockIdx.x * 64;
    int tid = threadIdx.x;
    int tr = tid / 16, tc = tid % 16;
    float acc[4][4] = {};
    for (int k0 = 0; k0 < K; k0 += 16) {
        {
            int ar = tid / 4;
            int ac = (tid % 4) * 4;
            int gm = m0 + ar;
            #pragma unroll
            for (int i = 0; i < 4; i++) {
                int gk = k0 + ac + i;
                As[ac + i][ar] = (gm < M && gk < K) ? A[(long)gm * lda + gk] : 0.f;
            }
        }
        if (!TRANSB) {
            int br = tid / 16;
            int bc = (tid % 16) * 4;
            int gk = k0 + br;
            #pragma unroll
            for (int i = 0; i < 4; i++) {
                int gn = n0 + bc + i;
                Bs[br][bc + i] = (gk < K && gn < N) ? B[(long)gk * ldb + gn] : 0.f;
            }
        } else {
            int bn = tid / 4;
            int bk = (tid % 4) * 4;
            int gn = n0 + bn;
            #pragma unroll
            for (int i = 0; i < 4; i++) {
                int gk = k0 + bk + i;
                Bs[bk + i][bn] = (gn < N && gk < K) ? B[(long)gn * ldb + gk] : 0.f;
            }
        }
        __syncthreads();
        #pragma unroll
        for (int kk = 0; kk < 16; kk++) {
            float a[4], b[4];
            #pragma unroll
            for (int i = 0; i < 4; i++) a[i] = As[kk][tr * 4 + i];
            #pragma unroll
            for (int i = 0; i < 4; i++) b[i] = Bs[kk][tc * 4 + i];
            #pragma unroll
            for (int i = 0; i < 4; i++)
                #pragma unroll
                for (int j = 0; j < 4; j++)
                    acc[i][j] += a[i] * b[j];
        }
        __syncthreads();
    }
    #pragma unroll
    for (int i = 0; i < 4; i++) {
        int gm = m0 + tr * 4 + i;
        if (gm >= M) continue;
        #pragma unroll
        for (int j = 0; j < 4; j++) {
            int gn = n0 + tc * 4 + j;
            if (gn >= N) continue;
            float v = acc[i][j] * alpha;
            long ci = (long)gm * ldc + gn;
            if (ACCUM) v += C[ci];
            if (bias) v += bias[gn];
            if (ACT == 1) v = fmaxf(v, 0.f);
            C[ci] = v;
        }
    }
}

static void launch_gemm(int transb, int act, int accum,
                        const float* A, int lda, long sA1, long sA2,
                        const float* B, int ldb, long sB1, long sB2,
                        float* C, int ldc, long sC1, long sC2,
                        const float* bias, int M, int N, int K, float alpha,
                        int batchH, int Z, hipStream_t st) {
    dim3 grid((N + 63) / 64, (M + 63) / 64, Z), blk(256);
#define GO(TB, A_, AC) gemm_k<TB, A_, AC><<<grid, blk, 0, st>>>(A, lda, sA1, sA2, B, ldb, sB1, sB2, C, ldc, sC1, sC2, bias, M, N, K, alpha, batchH)
    if (transb) {
        if (act) { if (accum) GO(1, 1, 1); else GO(1, 1, 0); }
        else     { if (accum) GO(1, 0, 1); else GO(1, 0, 0); }
    } else {
        if (act) { if (accum) GO(0, 1, 1); else GO(0, 1, 0); }
        else     { if (accum) GO(0, 0, 1); else GO(0, 0, 0); }
    }
#undef GO
}

// ================= conversions =================
// fp32 -> bf16, n % 8 == 0
__global__ void f2b_k(const float* __restrict__ in, ushort_t* __restrict__ out, long n) {
    long stride = (long)gridDim.x * blockDim.x * 8;
    for (long i = ((long)blockIdx.x * blockDim.x + threadIdx.x) * 8; i < n; i += stride) {
        float4 a = *(const float4*)(in + i);
        float4 b = *(const float4*)(in + i + 4);
        uint4 o;
        o.x = (unsigned)f2b(a.x) | ((unsigned)f2b(a.y) << 16);
        o.y = (unsigned)f2b(a.z) | ((unsigned)f2b(a.w) << 16);
        o.z = (unsigned)f2b(b.x) | ((unsigned)f2b(b.y) << 16);
        o.w = (unsigned)f2b(b.z) | ((unsigned)f2b(b.w) << 16);
        *(uint4*)(out + i) = o;
    }
}
// bf16(a+b)
__global__ void add_f2b_k(const float* __restrict__ a, const float* __restrict__ b,
                          ushort_t* __restrict__ out, long n) {
    long stride = (long)gridDim.x * blockDim.x * 8;
    for (long i = ((long)blockIdx.x * blockDim.x + threadIdx.x) * 8; i < n; i += stride) {
        float4 x = *(const float4*)(a + i);
        float4 y = *(const float4*)(b + i);
        float4 x2 = *(const float4*)(a + i + 4);
        float4 y2 = *(const float4*)(b + i + 4);
        uint4 o;
        o.x = (unsigned)f2b(x.x + y.x) | ((unsigned)f2b(x.y + y.y) << 16);
        o.y = (unsigned)f2b(x.z + y.z) | ((unsigned)f2b(x.w + y.w) << 16);
        o.z = (unsigned)f2b(x2.x + y2.x) | ((unsigned)f2b(x2.y + y2.y) << 16);
        o.w = (unsigned)f2b(x2.z + y2.z) | ((unsigned)f2b(x2.w + y2.w) << 16);
        *(uint4*)(out + i) = o;
    }
}
// transpose + convert: in (R x C) fp32 -> out (C x R) bf16, batched over z
__global__ void f2b_t_k(const float* __restrict__ in, ushort_t* __restrict__ out,
                        int R, int C, long inStride, long outStride) {
    __shared__ float tile[32][33];
    int z = blockIdx.z;
    in += z * inStride;
    out += z * outStride;
    int c0 = blockIdx.x * 32, r0 = blockIdx.y * 32;
    int tx = threadIdx.x, ty = threadIdx.y;
    #pragma unroll
    for (int i = 0; i < 32; i += 8) {
        int r = r0 + ty + i, c = c0 + tx;
        tile[ty + i][tx] = (r < R && c < C) ? in[(long)r * C + c] : 0.f;
    }
    __syncthreads();
    #pragma unroll
    for (int i = 0; i < 32; i += 8) {
        int c = c0 + ty + i, r = r0 + tx;
        if (c < C && r < R) out[(long)c * R + r] = f2b(tile[tx][ty + i]);
    }
}
__global__ void cat3_k(float* __restrict__ dst, const float* __restrict__ a,
                       const float* __restrict__ b, const float* __restrict__ c) {
    int t = blockIdx.x * blockDim.x + threadIdx.x;
    if (t < 512) dst[t] = a[t];
    else if (t < 1024) dst[t] = b[t - 512];
    else if (t < 1536) dst[t] = c[t - 1024];
}

// ---------------- elementwise ----------------
__global__ void addpos_k(const float* __restrict__ a, const float* __restrict__ pos,
                         float* __restrict__ o, long n, long pmod) {
    for (long i = blockIdx.x * (long)blockDim.x + threadIdx.x; i < n;
         i += (long)gridDim.x * blockDim.x)
        o[i] = a[i] + pos[i % pmod];
}
__global__ void zero_k(float* __restrict__ p, long n) {
    for (long i = blockIdx.x * (long)blockDim.x + threadIdx.x; i < n;
         i += (long)gridDim.x * blockDim.x)
        p[i] = 0.f;
}
__global__ void sentinel_k(float* p) { p[0] = 1e9f; }

// ---------------- residual + layernorm (in-place on x) ----------------
__global__ __launch_bounds__(256) void ln_res_k(float* __restrict__ x,
                                                const float* __restrict__ z,
                                                const float* __restrict__ g,
                                                const float* __restrict__ b) {
    long row = blockIdx.x;
    float* px = x + row * DD;
    const float* pz = z + row * DD;
    int t = threadIdx.x;
    float v0 = px[t] + pz[t];
    float v1 = px[t + 256] + pz[t + 256];
    float s = v0 + v1, sq = v0 * v0 + v1 * v1;
    for (int o = 32; o > 0; o >>= 1) {
        s += __shfl_xor(s, o, 64);
        sq += __shfl_xor(sq, o, 64);
    }
    __shared__ float ss[4], sqq[4];
    int wave = t >> 6, lane = t & 63;
    if (lane == 0) { ss[wave] = s; sqq[wave] = sq; }
    __syncthreads();
    s = ss[0] + ss[1] + ss[2] + ss[3];
    sq = sqq[0] + sqq[1] + sqq[2] + sqq[3];
    float mean = s * (1.f / DD);
    float var = sq * (1.f / DD) - mean * mean;
    float rstd = 1.f / sqrtf(var + 1e-5f);
    px[t] = (v0 - mean) * rstd * g[t] + b[t];
    px[t + 256] = (v1 - mean) * rstd * g[t + 256] + b[t + 256];
}

// ---------------- softmax over fp32 rows of length 128 ----------------
__global__ __launch_bounds__(256) void softmax128_k(float* __restrict__ s, long nrows) {
    int wave = threadIdx.x >> 6, lane = threadIdx.x & 63;
    long row = (long)blockIdx.x * 4 + wave;
    if (row >= nrows) return;
    float* p = s + row * 128;
    float a0 = p[lane], a1 = p[lane + 64];
    float m = fmaxf(a0, a1);
    for (int o = 32; o > 0; o >>= 1) m = fmaxf(m, __shfl_xor(m, o, 64));
    float e0 = expf(a0 - m), e1 = expf(a1 - m);
    float sum = e0 + e1;
    for (int o = 32; o > 0; o >>= 1) sum += __shfl_xor(sum, o, 64);
    float inv = 1.f / sum;
    p[lane] = e0 * inv;
    p[lane + 64] = e1 * inv;
}
// ---------------- softmax over bf16 rows of length 128 (in place) ----------------
__global__ __launch_bounds__(256) void softmax128_bf_k(ushort_t* __restrict__ s, long nrows) {
    int wave = threadIdx.x >> 6, lane = threadIdx.x & 63;
    long row = (long)blockIdx.x * 4 + wave;
    if (row >= nrows) return;
    ushort_t* p = s + row * 128;
    float a0 = b2f(p[lane]), a1 = b2f(p[lane + 64]);
    float m = fmaxf(a0, a1);
    for (int o = 32; o > 0; o >>= 1) m = fmaxf(m, __shfl_xor(m, o, 64));
    float e0 = expf(a0 - m), e1 = expf(a1 - m);
    float sum = e0 + e1;
    for (int o = 32; o > 0; o >>= 1) sum += __shfl_xor(sum, o, 64);
    float inv = 1.f / sum;
    p[lane] = f2b(e0 * inv);
    p[lane + 64] = f2b(e1 * inv);
}

// ---------------- conv helpers ----------------
// pad: fp_out (B,128,2000) fp32 -> fpp (B,130,2000) bf16, interior rows 1..128
__global__ void pad_copy_bf_k(const float* __restrict__ fp, ushort_t* __restrict__ fpp) {
    long total = (long)BB * TT * NW;
    for (long i = blockIdx.x * (long)blockDim.x + threadIdx.x; i < total;
         i += (long)gridDim.x * blockDim.x) {
        long ci = i % NW;
        long r = i / NW;
        long t = r % TT;
        long b = r / TT;
        fpp[(b * 130 + t + 1) * NW + ci] = f2b(fp[i]);
    }
}
// w[co][ci][kt] fp32 -> wk[kt][co][ci] bf16
__global__ void repack_bf_k(const float* __restrict__ w, ushort_t* __restrict__ wk,
                            int CO, int CI) {
    long total = (long)CO * CI * 3;
    for (long i = blockIdx.x * (long)blockDim.x + threadIdx.x; i < total;
         i += (long)gridDim.x * blockDim.x) {
        long kt = i % 3;
        long r = i / 3;
        long ci = r % CI;
        long co = r / CI;
        wk[kt * (long)CO * CI + co * CI + ci] = f2b(w[i]);
    }
}
// conv5 (128 -> 1) + sigmoid; h4 bf16 (B,130,128) channel-last
__global__ __launch_bounds__(128) void conv5_bf_k(const ushort_t* __restrict__ h4,
                                                  const float* __restrict__ w,
                                                  const float* __restrict__ bias,
                                                  float* __restrict__ out) {
    int b = blockIdx.x, t = threadIdx.x;
    __shared__ float wsm[384];
    wsm[t] = w[t];
    wsm[t + 128] = w[t + 128];
    wsm[t + 256] = w[t + 256];
    __syncthreads();
    const ushort_t* hb = h4 + (long)b * 130 * 128;
    float acc = bias[0];
    for (int ci = 0; ci < 128; ci++) {
        float w0 = wsm[ci * 3], w1 = wsm[ci * 3 + 1], w2 = wsm[ci * 3 + 2];
        acc += w0 * b2f(hb[(t + 0) * 128 + ci]) + w1 * b2f(hb[(t + 1) * 128 + ci]) +
               w2 * b2f(hb[(t + 2) * 128 + ci]);
    }
    out[b * TT + t] = 1.f / (1.f + expf(-acc));
}

// ---------------- masked segment softmax pooling ----------------
__global__ __launch_bounds__(128) void seg_pool_k(const float* __restrict__ weights,
                                                  const int* __restrict__ steds,
                                                  const float* __restrict__ vid,
                                                  float* __restrict__ segf) {
    int b = blockIdx.y, sidx = blockIdx.x;
    int st = steds[(b * SS + sidx) * 2];
    int ed = steds[(b * SS + sidx) * 2 + 1];
    int t = threadIdx.x;
    float w = (t >= st && t <= ed) ? weights[b * TT + t] : -1e30f;
    __shared__ float red[2];
    __shared__ float aw[TT];
    int wave = t >> 6, lane = t & 63;
    float m = w;
    for (int o = 32; o > 0; o >>= 1) m = fmaxf(m, __shfl_xor(m, o, 64));
    if (lane == 0) red[wave] = m;
    __syncthreads();
    m = fmaxf(red[0], red[1]);
    float e = expf(w - m);
    float sum = e;
    for (int o = 32; o > 0; o >>= 1) sum += __shfl_xor(sum, o, 64);
    __syncthreads();
    if (lane == 0) red[wave] = sum;
    __syncthreads();
    sum = red[0] + red[1];
    aw[t] = e / sum;
    __syncthreads();
    #pragma unroll
    for (int i = 0; i < 4; i++) {
        int d = t + i * 128;
        float acc = 0.f;
        for (int tt = 0; tt < TT; tt++)
            acc += aw[tt] * vid[((long)b * TT + tt) * DD + d];
        segf[((long)b * SS + sidx) * DD + d] = acc;
    }
}

extern "C" void kernel_launch(void* const* d_in, const int* in_sizes, int n_in,
                              void* d_out, int out_size, void* d_ws, size_t ws_size,
                              hipStream_t stream) {
    const float* vid = (const float*)d_in[0];
    const float* actn_feats = (const float*)d_in[2];
    const float* actn_concepts = (const float*)d_in[3];
    const float* pos = (const float*)d_in[4];
    const float* Wq = (const float*)d_in[5];
    const float* bq = (const float*)d_in[6];
    const float* Wk = (const float*)d_in[7];
    const float* bk = (const float*)d_in[8];
    const float* Wv = (const float*)d_in[9];
    const float* bv = (const float*)d_in[10];
    const float* Wo = (const float*)d_in[11];
    const float* bo = (const float*)d_in[12];
    const float* W1 = (const float*)d_in[13];
    const float* b1 = (const float*)d_in[14];
    const float* W2 = (const float*)d_in[15];
    const float* b2 = (const float*)d_in[16];
    const float* g1 = (const float*)d_in[17];
    const float* bb1 = (const float*)d_in[18];
    const float* g2 = (const float*)d_in[19];
    const float* bb2 = (const float*)d_in[20];
    const float* pqW = (const float*)d_in[21];
    const float* pqb = (const float*)d_in[22];
    const float* pkW = (const float*)d_in[23];
    const float* pkb = (const float*)d_in[24];
    const float* pvW = (const float*)d_in[25];
    const float* pvb = (const float*)d_in[26];
    const float* c1w = (const float*)d_in[27];
    const float* c1b = (const float*)d_in[28];
    const float* c2w = (const float*)d_in[29];
    const float* c2b = (const float*)d_in[30];
    const float* c3w = (const float*)d_in[31];
    const float* c3b = (const float*)d_in[32];
    const float* c4w = (const float*)d_in[33];
    const float* c4b = (const float*)d_in[34];
    const float* c5w = (const float*)d_in[35];
    const float* c5b = (const float*)d_in[36];
    const int* steds = (const int*)d_in[37];

    float* out = (float*)d_out;
    float* fc_out = out;            // 32*128
    float* al_out = out + 4096;     // 32*8*200
    float* fp_out = out + 55296;    // 32*128*2000

    float* ws = (float*)d_ws;
    const long NEED = 25165824;  // floats (~96 MB) — proven available in R1
    if (ws_size < (size_t)NEED * 4) {
        sentinel_k<<<1, 1, 0, stream>>>(fc_out);
        return;
    }

    // ---- arena (float-unit offsets; phases reuse wholesale) ----
    // persistent across phase A:
    const long XB      = 23000000;                 // x fp32 (2,097,152) -> 25,097,152
    // phase A:
    const long A_XBF   = 0;                        // x bf16      (1,048,576 fl-eq)
    const long A_QKV   = 1048576;                  // qkv fp32    (6,291,456)
    const long A_SB    = 7340032;                  // scores fp32 (4,194,304) / ffh bf16 alias
    const long A_AOB   = 11534336;                 // attn out fp32 (2,097,152)
    const long A_AOBF  = 13631488;                 // attn out bf16 (1,048,576)
    const long A_QB    = 14680064;                 // gemm scratch fp32 (2,097,152)
    const long A_WL    = 16777216;                 // per-layer weights bf16 + bias
    //   qkvT 393,216 | WoT 131,072 | W1T 524,288 | W2T 524,288 | qkvb 1,536
    // phase B:
    const long B_VPRBF = 2097152;                  // vproj bf16 (1,048,576)
    const long B_PW    = 3145728;                  // pqT/pkT/pvT bf16 (393,216)
    const long B_ACBF  = 3538944;                  // concepts bf16 (512,000)
    const long B_QPBF  = 4050944;                  // Qp bf16 (512,000)
    const long B_KPBF  = 4562944;                  // Kp bf16 (1,048,576)
    const long B_VP    = 5611520;                  // Vp fp32 (2,097,152)
    const long B_VPT   = 7708672;                  // VpT bf16 (1,048,576)
    const long B_SC    = 8757248;                  // scores bf16 chunk (8,192,000)
    const long B_UPD   = 16949248;                 // upd bf16 chunk (4,096,000)
    // phase C:
    const long C_FPP   = 0;                        // fpp bf16 (4,160,000)
    const long C_WK1   = 4160000;                  // 3,072,000
    const long C_WK2   = 7232000;                  // 786,432
    const long C_WK3   = 8018432;                  // 196,608
    const long C_WK4   = 8215040;                  // 49,152
    const long C_H1    = 8264192;                  // 2,129,920
    const long C_H2    = 10394112;                 // 1,064,960
    const long C_H3    = 11459072;                 // 532,480
    const long C_H4    = 11991552;                 // 266,240
    const long C_SEGF  = 12257792;                 // 131,072

    float* xb = ws + XB;
    const long nBTD = (long)BB * TT * DD;

    // x = vid + pos
    addpos_k<<<2048, 256, 0, stream>>>(vid, pos, xb, nBTD, (long)TT * DD);

    // ================= phase A: transformer =================
    ushort_t* xbf   = (ushort_t*)(ws + A_XBF);
    float*    qkv   = ws + A_QKV;
    float*    sb    = ws + A_SB;
    ushort_t* ffhbf = (ushort_t*)(ws + A_SB);
    float*    aob   = ws + A_AOB;
    ushort_t* aobf  = (ushort_t*)(ws + A_AOBF);
    float*    qb    = ws + A_QB;
    ushort_t* qkvT  = (ushort_t*)(ws + A_WL);
    ushort_t* WoT   = (ushort_t*)(ws + A_WL + 393216);
    ushort_t* W1T   = (ushort_t*)(ws + A_WL + 524288);
    ushort_t* W2T   = (ushort_t*)(ws + A_WL + 1048576);
    float*    qkvb  = ws + A_WL + 1572864;

    dim3 tblk(32, 8);
    for (int l = 0; l < LL; l++) {
        // weight prep (transpose+convert)
        f2b_t_k<<<dim3(16, 16, 1), tblk, 0, stream>>>(Wq + (long)l * DD * DD, qkvT, DD, DD, 0, 0);
        f2b_t_k<<<dim3(16, 16, 1), tblk, 0, stream>>>(Wk + (long)l * DD * DD, qkvT + 512 * 512, DD, DD, 0, 0);
        f2b_t_k<<<dim3(16, 16, 1), tblk, 0, stream>>>(Wv + (long)l * DD * DD, qkvT + 1024 * 512, DD, DD, 0, 0);
        f2b_t_k<<<dim3(16, 16, 1), tblk, 0, stream>>>(Wo + (long)l * DD * DD, WoT, DD, DD, 0, 0);
        f2b_t_k<<<dim3(64, 16, 1), tblk, 0, stream>>>(W1 + (long)l * DD * FF, W1T, DD, FF, 0, 0);
        f2b_t_k<<<dim3(16, 64, 1), tblk, 0, stream>>>(W2 + (long)l * FF * DD, W2T, FF, DD, 0, 0);
        cat3_k<<<6, 256, 0, stream>>>(qkvb, bq + (long)l * DD, bk + (long)l * DD, bv + (long)l * DD);

        // fused QKV projection (bf16 MFMA): (4096x512)@(512x1536) -> qkv fp32
        f2b_k<<<1024, 256, 0, stream>>>(xb, xbf, nBTD);
        launch_bgemm(0, 0, xbf, DD, 0, 0, qkvT, DD, 0, 0, qkv, 1536, 0, 0,
                     qkvb, BB * TT, 1536, DD, 1.f, 1, 1, 1, 0, 0, stream);
        // attention (fp32, per (b,h)): scores = q k^T / 8
        launch_gemm(1, 0, 0, qkv, 1536, (long)TT * 1536, HD,
                    qkv + 512, 1536, (long)TT * 1536, HD,
                    sb, TT, (long)HH * TT * TT, (long)TT * TT,
                    nullptr, TT, TT, HD, 0.125f, HH, BB * HH, stream);
        softmax128_k<<<(BB * HH * TT) / 4, 256, 0, stream>>>(sb, (long)BB * HH * TT);
        launch_gemm(0, 0, 0, sb, TT, (long)HH * TT * TT, (long)TT * TT,
                    qkv + 1024, 1536, (long)TT * 1536, HD,
                    aob, DD, (long)TT * DD, HD,
                    nullptr, TT, HD, TT, 1.f, HH, BB * HH, stream);
        // output projection
        f2b_k<<<1024, 256, 0, stream>>>(aob, aobf, nBTD);
        launch_bgemm(0, 0, aobf, DD, 0, 0, WoT, DD, 0, 0, qb, DD, 0, 0,
                     bo + (long)l * DD, BB * TT, DD, DD, 1.f, 1, 1, 1, 0, 0, stream);
        ln_res_k<<<BB * TT, 256, 0, stream>>>(xb, qb, g1 + (long)l * DD, bb1 + (long)l * DD);
        // FF
        f2b_k<<<1024, 256, 0, stream>>>(xb, xbf, nBTD);
        launch_bgemm(1, 1, xbf, DD, 0, 0, W1T, DD, 0, 0, ffhbf, FF, 0, 0,
                     b1 + (long)l * FF, BB * TT, FF, DD, 1.f, 1, 1, 1, 0, 0, stream);
        launch_bgemm(0, 0, ffhbf, FF, 0, 0, W2T, FF, 0, 0, qb, DD, 0, 0,
                     b2 + (long)l * DD, BB * TT, DD, FF, 1.f, 1, 1, 1, 0, 0, stream);
        ln_res_k<<<BB * TT, 256, 0, stream>>>(xb, qb, g2 + (long)l * DD, bb2 + (long)l * DD);
    }

    // ================= phase B: cross-attn + feats_proj =================
    ushort_t* vprbf = (ushort_t*)(ws + B_VPRBF);
    ushort_t* pqT   = (ushort_t*)(ws + B_PW);
    ushort_t* pkT   = (ushort_t*)(ws + B_PW + 131072);
    ushort_t* pvT   = (ushort_t*)(ws + B_PW + 262144);
    ushort_t* acbf  = (ushort_t*)(ws + B_ACBF);
    ushort_t* Qpbf  = (ushort_t*)(ws + B_QPBF);
    ushort_t* Kpbf  = (ushort_t*)(ws + B_KPBF);
    float*    Vp    = ws + B_VP;
    ushort_t* VpT   = (ushort_t*)(ws + B_VPT);
    ushort_t* scbf  = (ushort_t*)(ws + B_SC);
    ushort_t* updbf = (ushort_t*)(ws + B_UPD);

    add_f2b_k<<<1024, 256, 0, stream>>>(vid, xb, vprbf, nBTD);   // vproj (bf16)
    f2b_t_k<<<dim3(16, 16, 1), tblk, 0, stream>>>(pqW, pqT, DD, DD, 0, 0);
    f2b_t_k<<<dim3(16, 16, 1), tblk, 0, stream>>>(pkW, pkT, DD, DD, 0, 0);
    f2b_t_k<<<dim3(16, 16, 1), tblk, 0, stream>>>(pvW, pvT, DD, DD, 0, 0);
    f2b_k<<<512, 256, 0, stream>>>(actn_concepts, acbf, (long)NW * DD);

    launch_bgemm(0, 1, acbf, DD, 0, 0, pqT, DD, 0, 0, Qpbf, DD, 0, 0,
                 pqb, NW, DD, DD, 1.f, 1, 1, 1, 0, 0, stream);
    launch_bgemm(0, 1, vprbf, DD, 0, 0, pkT, DD, 0, 0, Kpbf, DD, 0, 0,
                 pkb, BB * TT, DD, DD, 1.f, 1, 1, 1, 0, 0, stream);
    launch_bgemm(0, 0, vprbf, DD, 0, 0, pvT, DD, 0, 0, Vp, DD, 0, 0,
                 pvb, BB * TT, DD, DD, 1.f, 1, 1, 1, 0, 0, stream);
    // VpT[b][d][t] = Vp[b][t][d]
    f2b_t_k<<<dim3(16, 4, 32), tblk, 0, stream>>>(Vp, VpT, TT, DD, (long)TT * DD, (long)TT * DD);

    const int CHUNK = 500;
    for (int c = 0; c < NW / CHUNK; c++) {
        int n0 = c * CHUNK;
        // scores[b,h,n,t] = Qp[n0+n,h,:] . Kp[b,t,h,:] / 8   (bf16 out)
        launch_bgemm(0, 1, Qpbf + (long)n0 * DD, DD, 0, 64,
                     Kpbf, DD, (long)TT * DD, 64,
                     scbf, TT, (long)HH * CHUNK * TT, (long)CHUNK * TT,
                     nullptr, CHUNK, TT, HD, 0.125f, HH, BB * HH, 1, 0, 0, stream);
        softmax128_bf_k<<<(BB * HH * CHUNK + 3) / 4, 256, 0, stream>>>(scbf, (long)BB * HH * CHUNK);
        // upd[b,n,h*64+d] = sum_t P[b,h,n,t] VpT[b,h*64+d,t]   (bf16 out)
        launch_bgemm(0, 1, scbf, TT, (long)HH * CHUNK * TT, (long)CHUNK * TT,
                     VpT, TT, (long)DD * TT, (long)HD * TT,
                     updbf, DD, (long)CHUNK * DD, 64,
                     nullptr, CHUNK, HD, TT, 1.f, HH, BB * HH, 1, 0, 0, stream);
        // fp[b,t,n0+n] = vproj[b,t,:] . upd[b,n,:]   (fp32 out to d_out)
        launch_bgemm(0, 0, vprbf, DD, (long)TT * DD, 0,
                     updbf, DD, (long)CHUNK * DD, 0,
                     fp_out + n0, NW, (long)TT * NW, 0,
                     nullptr, TT, CHUNK, DD, 1.f, 1, BB, 1, 0, 0, stream);
    }

    // ================= phase C: conv tower =================
    ushort_t* fpp = (ushort_t*)(ws + C_FPP);
    ushort_t* wk1 = (ushort_t*)(ws + C_WK1);
    ushort_t* wk2 = (ushort_t*)(ws + C_WK2);
    ushort_t* wk3 = (ushort_t*)(ws + C_WK3);
    ushort_t* wk4 = (ushort_t*)(ws + C_WK4);
    ushort_t* h1  = (ushort_t*)(ws + C_H1);
    ushort_t* h2  = (ushort_t*)(ws + C_H2);
    ushort_t* h3  = (ushort_t*)(ws + C_H3);
    ushort_t* h4  = (ushort_t*)(ws + C_H4);

    zero_k<<<4096, 256, 0, stream>>>(ws, C_SEGF);  // zero fpp+wk+h (incl. pads)
    repack_bf_k<<<1024, 256, 0, stream>>>(c1w, wk1, 1024, NW);
    repack_bf_k<<<512, 256, 0, stream>>>(c2w, wk2, 512, 1024);
    repack_bf_k<<<256, 256, 0, stream>>>(c3w, wk3, 256, 512);
    repack_bf_k<<<128, 256, 0, stream>>>(c4w, wk4, 128, 256);
    pad_copy_bf_k<<<2048, 256, 0, stream>>>(fp_out, fpp);

    // conv layers as taps=3 bf16 GEMM, activations (b, 130, C) channel-last
    launch_bgemm(1, 1, fpp, NW, (long)130 * NW, 0,
                 wk1, NW, 0, 0,
                 h1 + 1024, 1024, (long)130 * 1024, 0,
                 c1b, TT, 1024, NW, 1.f, 1, BB, 3, NW, (long)1024 * NW, stream);
    launch_bgemm(1, 1, h1, 1024, (long)130 * 1024, 0,
                 wk2, 1024, 0, 0,
                 h2 + 512, 512, (long)130 * 512, 0,
                 c2b, TT, 512, 1024, 1.f, 1, BB, 3, 1024, (long)512 * 1024, stream);
    launch_bgemm(1, 1, h2, 512, (long)130 * 512, 0,
                 wk3, 512, 0, 0,
                 h3 + 256, 256, (long)130 * 256, 0,
                 c3b, TT, 256, 512, 1.f, 1, BB, 3, 512, (long)256 * 512, stream);
    launch_bgemm(1, 1, h3, 256, (long)130 * 256, 0,
                 wk4, 256, 0, 0,
                 h4 + 128, 128, (long)130 * 128, 0,
                 c4b, TT, 128, 256, 1.f, 1, BB, 3, 256, (long)128 * 256, stream);
    conv5_bf_k<<<BB, 128, 0, stream>>>(h4, c5w, c5b, fc_out);

    // ================= segment pooling + logits (fp32) =================
    float* segf = ws + C_SEGF;
    seg_pool_k<<<dim3(SS, BB), 128, 0, stream>>>(fc_out, steds, vid, segf);
    launch_gemm(1, 0, 0, segf, DD, 0, 0, actn_feats, DD, 0, 0, al_out, NCC, 0, 0,
                nullptr, BB * SS, NCC, DD, 1.f, 1, 1, stream);
}

// Round 4
// 1681.682 us; speedup vs baseline: 5.2900x; 1.3828x over previous
//
#include <hip/hip_runtime.h>
#include <hip/hip_bf16.h>

// ---------------- constants ----------------
#define BB 32
#define TT 128
#define DD 512
#define NW 2000
#define NCC 200
#define SS 8
#define LL 4
#define HH 8
#define FF 2048
#define HD 64

typedef unsigned short ushort_t;
typedef __attribute__((ext_vector_type(8))) short bhalf8;
typedef __attribute__((ext_vector_type(4))) float floatx4;

__device__ inline ushort_t f2b(float x) {
    union { float f; unsigned int u; } v; v.f = x;
    unsigned int r = (v.u + 0x7FFFu + ((v.u >> 16) & 1u)) >> 16;
    return (ushort_t)r;
}
__device__ inline float b2f(ushort_t u) {
    union { unsigned int u; float f; } v; v.u = ((unsigned int)u) << 16;
    return v.f;
}
__device__ inline void gld16(const ushort_t* g, ushort_t* l) {
    __builtin_amdgcn_global_load_lds(
        (const __attribute__((address_space(1))) void*)g,
        (__attribute__((address_space(3))) void*)l, 16, 0, 0);
}

// ================= bf16 MFMA GEMM (2-phase pipelined, swizzled LDS) =========
// C[M,N] = act( alpha * sum_tap A[M,K] @ B[N,K]^T + bias )
// A: bf16 MxK row-major (lda). B: bf16 NxK row-major (ldb).
// batch z: zb=z/batchH, zh=z%batchH; offsets sA1*zb+sA2*zh etc (elements).
// taps: accumulate over tap with A += tap*tapA, B += tap*tapB (conv1d).
// LDS layout: tile row r (128), col c (64 bf16); byte = r*128 + ((2c)^((r&7)<<4)).
// Staged via global_load_lds (linear dest, pre-swizzled per-lane global src).
template<int ACT, int OUTBF>
__global__ __launch_bounds__(256) void bgemm_k(
    const ushort_t* __restrict__ A, int lda, long sA1, long sA2,
    const ushort_t* __restrict__ B, int ldb, long sB1, long sB2,
    void* __restrict__ Cv, int ldc, long sC1, long sC2,
    const float* __restrict__ bias,
    int M, int N, int K, float alpha, int batchH,
    int taps, long tapA, long tapB, const ushort_t* __restrict__ zbuf)
{
    __shared__ __align__(16) ushort_t sm[2][2][128 * 64];  // 64 KiB
    int z = blockIdx.z;
    int zb = z / batchH, zh = z % batchH;
    A += (long)zb * sA1 + (long)zh * sA2;
    B += (long)zb * sB1 + (long)zh * sB2;
    long cOff = (long)zb * sC1 + (long)zh * sC2;
    int m0 = blockIdx.y * 128, n0 = blockIdx.x * 128;
    int tid = threadIdx.x;
    int wid = tid >> 6, lane = tid & 63;
    int wr = wid >> 1, wc = wid & 1;
    int lr = lane & 15, lg = lane >> 4;

    int kSteps = (K + 63) >> 6;
    int nt = taps * kSteps;

    // staging geometry: per wave-instr i, rows r0=wid*32+i*8 .. +7
    int rsub = lane >> 3;                 // 0..7 (row within 8-row group)
    int ssub = lane & 7;                  // 16B chunk within row
    int scol = ((ssub ^ rsub) << 3);      // pre-swizzled logical col (bf16)
    bool aok[4], bok[4];
    const ushort_t* aptr[4];
    const ushort_t* bptr[4];
    #pragma unroll
    for (int i = 0; i < 4; i++) {
        int row = (wid << 5) + (i << 3) + rsub;
        aok[i] = (m0 + row) < M;
        bok[i] = (n0 + row) < N;
        aptr[i] = A + (long)(m0 + row) * lda + scol;
        bptr[i] = B + (long)(n0 + row) * ldb + scol;
    }

    floatx4 acc[4][4];
    #pragma unroll
    for (int i = 0; i < 4; i++)
        #pragma unroll
        for (int j = 0; j < 4; j++)
            acc[i][j] = (floatx4){0.f, 0.f, 0.f, 0.f};

    // --- prologue: stage tile 0 into buffer 0 ---
    {
        bool kOk = scol < K;
        #pragma unroll
        for (int i = 0; i < 4; i++) {
            const ushort_t* as = (kOk && aok[i]) ? aptr[i] : zbuf;
            const ushort_t* bs = (kOk && bok[i]) ? bptr[i] : zbuf;
            int lb = ((wid << 5) + (i << 3)) << 6;
            gld16(as, &sm[0][0][lb]);
            gld16(bs, &sm[0][1][lb]);
        }
    }
    __syncthreads();

    int cur = 0;
    int tap_n = 0, k0_n = 0;
    for (int t = 0; t < nt; t++) {
        // advance to step t+1 and prefetch into other buffer
        k0_n += 64;
        if (k0_n >= K) { k0_n = 0; ++tap_n; }
        if (tap_n < taps) {
            bool kOk = (k0_n + scol) < K;
            #pragma unroll
            for (int i = 0; i < 4; i++) {
                const ushort_t* as =
                    (kOk && aok[i]) ? (aptr[i] + (long)tap_n * tapA + k0_n) : zbuf;
                const ushort_t* bs =
                    (kOk && bok[i]) ? (bptr[i] + (long)tap_n * tapB + k0_n) : zbuf;
                int lb = ((wid << 5) + (i << 3)) << 6;
                gld16(as, &sm[cur ^ 1][0][lb]);
                gld16(bs, &sm[cur ^ 1][1][lb]);
            }
        }
        // compute on current buffer (swizzled ds_read)
        const char* Ab = (const char*)&sm[cur][0][0];
        const char* Bbs = (const char*)&sm[cur][1][0];
        #pragma unroll
        for (int kk = 0; kk < 2; kk++) {
            bhalf8 a_[4], b_[4];
            #pragma unroll
            for (int i = 0; i < 4; i++) {
                int r = wr * 64 + i * 16 + lr;
                int off = (r << 7) + (((kk << 6) + (lg << 4)) ^ ((r & 7) << 4));
                a_[i] = *(const bhalf8*)(Ab + off);
            }
            #pragma unroll
            for (int j = 0; j < 4; j++) {
                int r = wc * 64 + j * 16 + lr;
                int off = (r << 7) + (((kk << 6) + (lg << 4)) ^ ((r & 7) << 4));
                b_[j] = *(const bhalf8*)(Bbs + off);
            }
            #pragma unroll
            for (int i = 0; i < 4; i++)
                #pragma unroll
                for (int j = 0; j < 4; j++)
                    acc[i][j] = __builtin_amdgcn_mfma_f32_16x16x32_bf16(
                        a_[i], b_[j], acc[i][j], 0, 0, 0);
        }
        __syncthreads();   // drains vmcnt (prefetch) + lgkm; swap safe
        cur ^= 1;
    }

    // epilogue: C/D layout col=lane&15, row=(lane>>4)*4+reg  [m89-verified]
    #pragma unroll
    for (int i = 0; i < 4; i++) {
        int gm_base = m0 + wr * 64 + i * 16 + lg * 4;
        #pragma unroll
        for (int j = 0; j < 4; j++) {
            int gn = n0 + wc * 64 + j * 16 + lr;
            if (gn >= N) continue;
            float bv = bias ? bias[gn] : 0.f;
            #pragma unroll
            for (int r = 0; r < 4; r++) {
                int gm = gm_base + r;
                if (gm >= M) continue;
                float v = acc[i][j][r] * alpha + bv;
                if (ACT == 1) v = fmaxf(v, 0.f);
                long idx = cOff + (long)gm * ldc + gn;
                if (OUTBF) ((ushort_t*)Cv)[idx] = f2b(v);
                else       ((float*)Cv)[idx] = v;
            }
        }
    }
}

static void launch_bgemm(int act, int outbf,
                         const ushort_t* A, int lda, long sA1, long sA2,
                         const ushort_t* B, int ldb, long sB1, long sB2,
                         void* C, int ldc, long sC1, long sC2,
                         const float* bias, int M, int N, int K, float alpha,
                         int batchH, int Z, int taps, long tapA, long tapB,
                         const ushort_t* zbuf, hipStream_t st) {
    dim3 grid((N + 127) / 128, (M + 127) / 128, Z), blk(256);
#define BG(A_, O_) bgemm_k<A_, O_><<<grid, blk, 0, st>>>(A, lda, sA1, sA2, B, ldb, sB1, sB2, C, ldc, sC1, sC2, bias, M, N, K, alpha, batchH, taps, tapA, tapB, zbuf)
    if (act) { if (outbf) BG(1, 1); else BG(1, 0); }
    else     { if (outbf) BG(0, 1); else BG(0, 0); }
#undef BG
}

// ================= fp32 tiled GEMM (small/sensitive ops) =================
template<int TRANSB, int ACT, int OUTBF>
__global__ __launch_bounds__(256) void gemm_k(
    const float* __restrict__ A, int lda, long sA1, long sA2,
    const float* __restrict__ B, int ldb, long sB1, long sB2,
    void* __restrict__ Cv, int ldc, long sC1, long sC2,
    const float* __restrict__ bias,
    int M, int N, int K, float alpha, int batchH)
{
    __shared__ float As[16][68];
    __shared__ float Bs[16][68];
    int z = blockIdx.z;
    int zb = z / batchH, zh = z % batchH;
    A += (long)zb * sA1 + (long)zh * sA2;
    B += (long)zb * sB1 + (long)zh * sB2;
    long cOff = (long)zb * sC1 + (long)zh * sC2;
    int m0 = blockIdx.y * 64, n0 = blockIdx.x * 64;
    int tid = threadIdx.x;
    int tr = tid / 16, tc = tid % 16;
    float acc[4][4] = {};
    for (int k0 = 0; k0 < K; k0 += 16) {
        {
            int ar = tid / 4;
            int ac = (tid % 4) * 4;
            int gm = m0 + ar;
            #pragma unroll
            for (int i = 0; i < 4; i++) {
                int gk = k0 + ac + i;
                As[ac + i][ar] = (gm < M && gk < K) ? A[(long)gm * lda + gk] : 0.f;
            }
        }
        if (!TRANSB) {
            int br = tid / 16;
            int bc = (tid % 16) * 4;
            int gk = k0 + br;
            #pragma unroll
            for (int i = 0; i < 4; i++) {
                int gn = n0 + bc + i;
                Bs[br][bc + i] = (gk < K && gn < N) ? B[(long)gk * ldb + gn] : 0.f;
            }
        } else {
            int bn = tid / 4;
            int bk = (tid % 4) * 4;
            int gn = n0 + bn;
            #pragma unroll
            for (int i = 0; i < 4; i++) {
                int gk = k0 + bk + i;
                Bs[bk + i][bn] = (gn < N && gk < K) ? B[(long)gn * ldb + gk] : 0.f;
            }
        }
        __syncthreads();
        #pragma unroll
        for (int kk = 0; kk < 16; kk++) {
            float a[4], b[4];
            #pragma unroll
            for (int i = 0; i < 4; i++) a[i] = As[kk][tr * 4 + i];
            #pragma unroll
            for (int i = 0; i < 4; i++) b[i] = Bs[kk][tc * 4 + i];
            #pragma unroll
            for (int i = 0; i < 4; i++)
                #pragma unroll
                for (int j = 0; j < 4; j++)
                    acc[i][j] += a[i] * b[j];
        }
        __syncthreads();
    }
    #pragma unroll
    for (int i = 0; i < 4; i++) {
        int gm = m0 + tr * 4 + i;
        if (gm >= M) continue;
        #pragma unroll
        for (int j = 0; j < 4; j++) {
            int gn = n0 + tc * 4 + j;
            if (gn >= N) continue;
            float v = acc[i][j] * alpha;
            if (bias) v += bias[gn];
            if (ACT == 1) v = fmaxf(v, 0.f);
            long ci = cOff + (long)gm * ldc + gn;
            if (OUTBF) ((ushort_t*)Cv)[ci] = f2b(v);
            else       ((float*)Cv)[ci] = v;
        }
    }
}

static void launch_gemm(int transb, int act, int outbf,
                        const float* A, int lda, long sA1, long sA2,
                        const float* B, int ldb, long sB1, long sB2,
                        void* C, int ldc, long sC1, long sC2,
                        const float* bias, int M, int N, int K, float alpha,
                        int batchH, int Z, hipStream_t st) {
    dim3 grid((N + 63) / 64, (M + 63) / 64, Z), blk(256);
#define GO(TB, A_, O_) gemm_k<TB, A_, O_><<<grid, blk, 0, st>>>(A, lda, sA1, sA2, B, ldb, sB1, sB2, C, ldc, sC1, sC2, bias, M, N, K, alpha, batchH)
    if (transb) {
        if (act) { if (outbf) GO(1, 1, 1); else GO(1, 1, 0); }
        else     { if (outbf) GO(1, 0, 1); else GO(1, 0, 0); }
    } else {
        if (act) { if (outbf) GO(0, 1, 1); else GO(0, 1, 0); }
        else     { if (outbf) GO(0, 0, 1); else GO(0, 0, 0); }
    }
#undef GO
}

// ================= conversions =================
__global__ void f2b_k(const float* __restrict__ in, ushort_t* __restrict__ out, long n) {
    long stride = (long)gridDim.x * blockDim.x * 8;
    for (long i = ((long)blockIdx.x * blockDim.x + threadIdx.x) * 8; i < n; i += stride) {
        float4 a = *(const float4*)(in + i);
        float4 b = *(const float4*)(in + i + 4);
        uint4 o;
        o.x = (unsigned)f2b(a.x) | ((unsigned)f2b(a.y) << 16);
        o.y = (unsigned)f2b(a.z) | ((unsigned)f2b(a.w) << 16);
        o.z = (unsigned)f2b(b.x) | ((unsigned)f2b(b.y) << 16);
        o.w = (unsigned)f2b(b.z) | ((unsigned)f2b(b.w) << 16);
        *(uint4*)(out + i) = o;
    }
}
__global__ void add_f2b_k(const float* __restrict__ a, const float* __restrict__ b,
                          ushort_t* __restrict__ out, long n) {
    long stride = (long)gridDim.x * blockDim.x * 8;
    for (long i = ((long)blockIdx.x * blockDim.x + threadIdx.x) * 8; i < n; i += stride) {
        float4 x = *(const float4*)(a + i);
        float4 y = *(const float4*)(b + i);
        float4 x2 = *(const float4*)(a + i + 4);
        float4 y2 = *(const float4*)(b + i + 4);
        uint4 o;
        o.x = (unsigned)f2b(x.x + y.x) | ((unsigned)f2b(x.y + y.y) << 16);
        o.y = (unsigned)f2b(x.z + y.z) | ((unsigned)f2b(x.w + y.w) << 16);
        o.z = (unsigned)f2b(x2.x + y2.x) | ((unsigned)f2b(x2.y + y2.y) << 16);
        o.w = (unsigned)f2b(x2.z + y2.z) | ((unsigned)f2b(x2.w + y2.w) << 16);
        *(uint4*)(out + i) = o;
    }
}
// transpose + convert: in (R x C) fp32 -> out (C x R) bf16, batched over z
__global__ void f2b_t_k(const float* __restrict__ in, ushort_t* __restrict__ out,
                        int R, int C, long inStride, long outStride) {
    __shared__ float tile[32][33];
    int z = blockIdx.z;
    in += (long)z * inStride;
    out += (long)z * outStride;
    int c0 = blockIdx.x * 32, r0 = blockIdx.y * 32;
    int tx = threadIdx.x, ty = threadIdx.y;
    #pragma unroll
    for (int i = 0; i < 32; i += 8) {
        int r = r0 + ty + i, c = c0 + tx;
        tile[ty + i][tx] = (r < R && c < C) ? in[(long)r * C + c] : 0.f;
    }
    __syncthreads();
    #pragma unroll
    for (int i = 0; i < 32; i += 8) {
        int c = c0 + ty + i, r = r0 + tx;
        if (c < C && r < R) out[(long)c * R + r] = f2b(tile[tx][ty + i]);
    }
}
// all-layer qkv bias concat
__global__ void cat3all_k(float* __restrict__ dst, const float* __restrict__ a,
                          const float* __restrict__ b, const float* __restrict__ c) {
    int i = blockIdx.x * blockDim.x + threadIdx.x;
    if (i >= LL * 1536) return;
    int l = i / 1536, j = i % 1536;
    float v = (j < 512) ? a[l * 512 + j]
            : (j < 1024) ? b[l * 512 + j - 512] : c[l * 512 + j - 1024];
    dst[i] = v;
}

// ---------------- elementwise ----------------
__global__ void addpos_bf_k(const float* __restrict__ a, const float* __restrict__ pos,
                            float* __restrict__ o, ushort_t* __restrict__ obf,
                            long n, long pmod) {
    for (long i = blockIdx.x * (long)blockDim.x + threadIdx.x; i < n;
         i += (long)gridDim.x * blockDim.x) {
        float v = a[i] + pos[i % pmod];
        o[i] = v;
        obf[i] = f2b(v);
    }
}
__global__ void zero_k(float* __restrict__ p, long n) {
    for (long i = blockIdx.x * (long)blockDim.x + threadIdx.x; i < n;
         i += (long)gridDim.x * blockDim.x)
        p[i] = 0.f;
}
__global__ void sentinel_k(float* p) { p[0] = 1e9f; }

// ---------------- residual + layernorm (in-place on x, bf16 mirror) --------
__global__ __launch_bounds__(256) void ln_res_k(float* __restrict__ x,
                                                const float* __restrict__ z,
                                                ushort_t* __restrict__ xbf,
                                                const float* __restrict__ g,
                                                const float* __restrict__ b) {
    long row = blockIdx.x;
    float* px = x + row * DD;
    const float* pz = z + row * DD;
    ushort_t* pb = xbf + row * DD;
    int t = threadIdx.x;
    float v0 = px[t] + pz[t];
    float v1 = px[t + 256] + pz[t + 256];
    float s = v0 + v1, sq = v0 * v0 + v1 * v1;
    for (int o = 32; o > 0; o >>= 1) {
        s += __shfl_xor(s, o, 64);
        sq += __shfl_xor(sq, o, 64);
    }
    __shared__ float ss[4], sqq[4];
    int wave = t >> 6, lane = t & 63;
    if (lane == 0) { ss[wave] = s; sqq[wave] = sq; }
    __syncthreads();
    s = ss[0] + ss[1] + ss[2] + ss[3];
    sq = sqq[0] + sqq[1] + sqq[2] + sqq[3];
    float mean = s * (1.f / DD);
    float var = sq * (1.f / DD) - mean * mean;
    float rstd = 1.f / sqrtf(var + 1e-5f);
    float o0 = (v0 - mean) * rstd * g[t] + b[t];
    float o1 = (v1 - mean) * rstd * g[t + 256] + b[t + 256];
    px[t] = o0;
    px[t + 256] = o1;
    pb[t] = f2b(o0);
    pb[t + 256] = f2b(o1);
}

// ---------------- softmax (len 128) ----------------
__global__ __launch_bounds__(256) void softmax128_k(float* __restrict__ s, long nrows) {
    int wave = threadIdx.x >> 6, lane = threadIdx.x & 63;
    long row = (long)blockIdx.x * 4 + wave;
    if (row >= nrows) return;
    float* p = s + row * 128;
    float a0 = p[lane], a1 = p[lane + 64];
    float m = fmaxf(a0, a1);
    for (int o = 32; o > 0; o >>= 1) m = fmaxf(m, __shfl_xor(m, o, 64));
    float e0 = expf(a0 - m), e1 = expf(a1 - m);
    float sum = e0 + e1;
    for (int o = 32; o > 0; o >>= 1) sum += __shfl_xor(sum, o, 64);
    float inv = 1.f / sum;
    p[lane] = e0 * inv;
    p[lane + 64] = e1 * inv;
}
__global__ __launch_bounds__(256) void softmax128_bf_k(ushort_t* __restrict__ s, long nrows) {
    int wave = threadIdx.x >> 6, lane = threadIdx.x & 63;
    long row = (long)blockIdx.x * 4 + wave;
    if (row >= nrows) return;
    ushort_t* p = s + row * 128;
    float a0 = b2f(p[lane]), a1 = b2f(p[lane + 64]);
    float m = fmaxf(a0, a1);
    for (int o = 32; o > 0; o >>= 1) m = fmaxf(m, __shfl_xor(m, o, 64));
    float e0 = expf(a0 - m), e1 = expf(a1 - m);
    float sum = e0 + e1;
    for (int o = 32; o > 0; o >>= 1) sum += __shfl_xor(sum, o, 64);
    float inv = 1.f / sum;
    p[lane] = f2b(e0 * inv);
    p[lane + 64] = f2b(e1 * inv);
}

// ---------------- conv helpers ----------------
__global__ void pad_copy_bf_k(const float* __restrict__ fp, ushort_t* __restrict__ fpp) {
    long total = (long)BB * TT * NW;
    for (long i = blockIdx.x * (long)blockDim.x + threadIdx.x; i < total;
         i += (long)gridDim.x * blockDim.x) {
        long ci = i % NW;
        long r = i / NW;
        long t = r % TT;
        long b = r / TT;
        fpp[(b * 130 + t + 1) * NW + ci] = f2b(fp[i]);
    }
}
__global__ void repack_bf_k(const float* __restrict__ w, ushort_t* __restrict__ wk,
                            int CO, int CI) {
    long total = (long)CO * CI * 3;
    for (long i = blockIdx.x * (long)blockDim.x + threadIdx.x; i < total;
         i += (long)gridDim.x * blockDim.x) {
        long kt = i % 3;
        long r = i / 3;
        long ci = r % CI;
        long co = r / CI;
        wk[kt * (long)CO * CI + co * CI + ci] = f2b(w[i]);
    }
}
__global__ __launch_bounds__(128) void conv5_bf_k(const ushort_t* __restrict__ h4,
                                                  const float* __restrict__ w,
                                                  const float* __restrict__ bias,
                                                  float* __restrict__ out) {
    int b = blockIdx.x, t = threadIdx.x;
    __shared__ float wsm[384];
    wsm[t] = w[t];
    wsm[t + 128] = w[t + 128];
    wsm[t + 256] = w[t + 256];
    __syncthreads();
    const ushort_t* hb = h4 + (long)b * 130 * 128;
    float acc = bias[0];
    for (int ci = 0; ci < 128; ci++) {
        float w0 = wsm[ci * 3], w1 = wsm[ci * 3 + 1], w2 = wsm[ci * 3 + 2];
        acc += w0 * b2f(hb[(t + 0) * 128 + ci]) + w1 * b2f(hb[(t + 1) * 128 + ci]) +
               w2 * b2f(hb[(t + 2) * 128 + ci]);
    }
    out[b * TT + t] = 1.f / (1.f + expf(-acc));
}

// ---------------- masked segment softmax pooling ----------------
__global__ __launch_bounds__(128) void seg_pool_k(const float* __restrict__ weights,
                                                  const int* __restrict__ steds,
                                                  const float* __restrict__ vid,
                                                  float* __restrict__ segf) {
    int b = blockIdx.y, sidx = blockIdx.x;
    int st = steds[(b * SS + sidx) * 2];
    int ed = steds[(b * SS + sidx) * 2 + 1];
    int t = threadIdx.x;
    float w = (t >= st && t <= ed) ? weights[b * TT + t] : -1e30f;
    __shared__ float red[2];
    __shared__ float aw[TT];
    int wave = t >> 6, lane = t & 63;
    float m = w;
    for (int o = 32; o > 0; o >>= 1) m = fmaxf(m, __shfl_xor(m, o, 64));
    if (lane == 0) red[wave] = m;
    __syncthreads();
    m = fmaxf(red[0], red[1]);
    float e = expf(w - m);
    float sum = e;
    for (int o = 32; o > 0; o >>= 1) sum += __shfl_xor(sum, o, 64);
    __syncthreads();
    if (lane == 0) red[wave] = sum;
    __syncthreads();
    sum = red[0] + red[1];
    aw[t] = e / sum;
    __syncthreads();
    #pragma unroll
    for (int i = 0; i < 4; i++) {
        int d = t + i * 128;
        float acc = 0.f;
        for (int tt = 0; tt < TT; tt++)
            acc += aw[tt] * vid[((long)b * TT + tt) * DD + d];
        segf[((long)b * SS + sidx) * DD + d] = acc;
    }
}

extern "C" void kernel_launch(void* const* d_in, const int* in_sizes, int n_in,
                              void* d_out, int out_size, void* d_ws, size_t ws_size,
                              hipStream_t stream) {
    const float* vid = (const float*)d_in[0];
    const float* actn_feats = (const float*)d_in[2];
    const float* actn_concepts = (const float*)d_in[3];
    const float* pos = (const float*)d_in[4];
    const float* Wq = (const float*)d_in[5];
    const float* bq = (const float*)d_in[6];
    const float* Wk = (const float*)d_in[7];
    const float* bk = (const float*)d_in[8];
    const float* Wv = (const float*)d_in[9];
    const float* bv = (const float*)d_in[10];
    const float* Wo = (const float*)d_in[11];
    const float* bo = (const float*)d_in[12];
    const float* W1 = (const float*)d_in[13];
    const float* b1 = (const float*)d_in[14];
    const float* W2 = (const float*)d_in[15];
    const float* b2 = (const float*)d_in[16];
    const float* g1 = (const float*)d_in[17];
    const float* bb1 = (const float*)d_in[18];
    const float* g2 = (const float*)d_in[19];
    const float* bb2 = (const float*)d_in[20];
    const float* pqW = (const float*)d_in[21];
    const float* pqb = (const float*)d_in[22];
    const float* pkW = (const float*)d_in[23];
    const float* pkb = (const float*)d_in[24];
    const float* pvW = (const float*)d_in[25];
    const float* pvb = (const float*)d_in[26];
    const float* c1w = (const float*)d_in[27];
    const float* c1b = (const float*)d_in[28];
    const float* c2w = (const float*)d_in[29];
    const float* c2b = (const float*)d_in[30];
    const float* c3w = (const float*)d_in[31];
    const float* c3b = (const float*)d_in[32];
    const float* c4w = (const float*)d_in[33];
    const float* c4b = (const float*)d_in[34];
    const float* c5w = (const float*)d_in[35];
    const float* c5b = (const float*)d_in[36];
    const int* steds = (const int*)d_in[37];

    float* out = (float*)d_out;
    float* fc_out = out;            // 32*128
    float* al_out = out + 4096;     // 32*8*200
    float* fp_out = out + 55296;    // 32*128*2000

    float* ws = (float*)d_ws;
    const long NEED = 25165824;  // floats (~96 MB) — proven available
    if (ws_size < (size_t)NEED * 4) {
        sentinel_k<<<1, 1, 0, stream>>>(fc_out);
        return;
    }

    // ---- arena (float-unit offsets) ----
    // phase A:
    const long A_XBF   = 0;          // x bf16 (1,048,576)
    const long A_QKV   = 1048576;    // qkv fp32 (6,291,456) -> 7,340,032
    const long A_SB    = 7340032;    // scores fp32 (4,194,304) / ffh bf16 alias -> 11,534,336
    const long A_AOBF  = 11534336;   // attn out bf16 (1,048,576) -> 12,582,912
    const long A_QB    = 12582912;   // gemm scratch fp32 (2,097,152) -> 14,680,064
    const long A_QKVT  = 14680064;   // qkvT all layers bf16 (1,572,864 fl) -> 16,252,928
    const long A_WOT   = 16252928;   // WoT all layers (524,288) -> 16,777,216
    const long A_W1T   = 16777216;   // W1T all layers (2,097,152) -> 18,874,368
    const long A_W2T   = 18874368;   // W2T all layers (2,097,152) -> 20,971,520
    const long A_QKVB  = 20971520;   // qkv bias all layers (6,144) -> 20,977,664
    const long XB      = 21000192;   // x fp32 (2,097,152) -> 23,097,344
    const long ZPAD    = 23100416;   // 64 zero floats (zbuf for bgemm)
    // phase B:
    const long B_VPRBF = 2097152;    // vproj bf16 (1,048,576)
    const long B_PW    = 3145728;    // pqT/pkT/pvT bf16 (393,216)
    const long B_ACBF  = 3538944;    // concepts bf16 (512,000)
    const long B_QPBF  = 4050944;    // Qp bf16 (512,000)
    const long B_KPBF  = 4562944;    // Kp bf16 (1,048,576)
    const long B_VP    = 5611520;    // Vp fp32 (2,097,152)
    const long B_VPT   = 7708672;    // VpT bf16 (1,048,576)
    const long B_SC    = 8757248;    // scores bf16 chunk (8,192,000)
    const long B_UPD   = 16949248;   // upd bf16 chunk (4,096,000) (xb dead by then)
    // phase C:
    const long C_FPP   = 0;
    const long C_WK1   = 4160000;
    const long C_WK2   = 7232000;
    const long C_WK3   = 8018432;
    const long C_WK4   = 8215040;
    const long C_H1    = 8264192;
    const long C_H2    = 10394112;
    const long C_H3    = 11459072;
    const long C_H4    = 11991552;
    const long C_SEGF  = 12257792;

    float* xb = ws + XB;
    const ushort_t* zbuf = (const ushort_t*)(ws + ZPAD);
    const long nBTD = (long)BB * TT * DD;

    zero_k<<<1, 64, 0, stream>>>(ws + ZPAD, 64);

    // x = vid + pos (fp32 + bf16 mirror)
    ushort_t* xbf = (ushort_t*)(ws + A_XBF);
    addpos_bf_k<<<2048, 256, 0, stream>>>(vid, pos, xb, xbf, nBTD, (long)TT * DD);

    // ---- all-layer weight prep (batched over z=L) ----
    ushort_t* qkvT = (ushort_t*)(ws + A_QKVT);
    ushort_t* WoT  = (ushort_t*)(ws + A_WOT);
    ushort_t* W1T  = (ushort_t*)(ws + A_W1T);
    ushort_t* W2T  = (ushort_t*)(ws + A_W2T);
    float*    qkvb = ws + A_QKVB;
    dim3 tblk(32, 8);
    f2b_t_k<<<dim3(16, 16, LL), tblk, 0, stream>>>(Wq, qkvT, DD, DD, (long)DD * DD, 786432);
    f2b_t_k<<<dim3(16, 16, LL), tblk, 0, stream>>>(Wk, qkvT + 262144, DD, DD, (long)DD * DD, 786432);
    f2b_t_k<<<dim3(16, 16, LL), tblk, 0, stream>>>(Wv, qkvT + 524288, DD, DD, (long)DD * DD, 786432);
    f2b_t_k<<<dim3(16, 16, LL), tblk, 0, stream>>>(Wo, WoT, DD, DD, (long)DD * DD, 262144);
    f2b_t_k<<<dim3(64, 16, LL), tblk, 0, stream>>>(W1, W1T, DD, FF, (long)DD * FF, 1048576);
    f2b_t_k<<<dim3(16, 64, LL), tblk, 0, stream>>>(W2, W2T, FF, DD, (long)FF * DD, 1048576);
    cat3all_k<<<(LL * 1536 + 255) / 256, 256, 0, stream>>>(qkvb, bq, bk, bv);

    // ================= phase A: transformer =================
    float*    qkv   = ws + A_QKV;
    float*    sb    = ws + A_SB;
    ushort_t* ffhbf = (ushort_t*)(ws + A_SB);
    ushort_t* aobf  = (ushort_t*)(ws + A_AOBF);
    float*    qb    = ws + A_QB;

    for (int l = 0; l < LL; l++) {
        // fused QKV projection (bf16 MFMA)
        launch_bgemm(0, 0, xbf, DD, 0, 0, qkvT + (long)l * 786432, DD, 0, 0,
                     qkv, 1536, 0, 0, qkvb + (long)l * 1536,
                     BB * TT, 1536, DD, 1.f, 1, 1, 1, 0, 0, zbuf, stream);
        // attention (fp32): scores = q k^T / 8
        launch_gemm(1, 0, 0, qkv, 1536, (long)TT * 1536, HD,
                    qkv + 512, 1536, (long)TT * 1536, HD,
                    sb, TT, (long)HH * TT * TT, (long)TT * TT,
                    nullptr, TT, TT, HD, 0.125f, HH, BB * HH, stream);
        softmax128_k<<<(BB * HH * TT) / 4, 256, 0, stream>>>(sb, (long)BB * HH * TT);
        // PV (fp32 in, bf16 out)
        launch_gemm(0, 0, 1, sb, TT, (long)HH * TT * TT, (long)TT * TT,
                    qkv + 1024, 1536, (long)TT * 1536, HD,
                    aobf, DD, (long)TT * DD, HD,
                    nullptr, TT, HD, TT, 1.f, HH, BB * HH, stream);
        // output projection
        launch_bgemm(0, 0, aobf, DD, 0, 0, WoT + (long)l * 262144, DD, 0, 0,
                     qb, DD, 0, 0, bo + (long)l * DD,
                     BB * TT, DD, DD, 1.f, 1, 1, 1, 0, 0, zbuf, stream);
        ln_res_k<<<BB * TT, 256, 0, stream>>>(xb, qb, xbf, g1 + (long)l * DD, bb1 + (long)l * DD);
        // FF
        launch_bgemm(1, 1, xbf, DD, 0, 0, W1T + (long)l * 1048576, DD, 0, 0,
                     ffhbf, FF, 0, 0, b1 + (long)l * FF,
                     BB * TT, FF, DD, 1.f, 1, 1, 1, 0, 0, zbuf, stream);
        launch_bgemm(0, 0, ffhbf, FF, 0, 0, W2T + (long)l * 1048576, FF, 0, 0,
                     qb, DD, 0, 0, b2 + (long)l * DD,
                     BB * TT, DD, FF, 1.f, 1, 1, 1, 0, 0, zbuf, stream);
        ln_res_k<<<BB * TT, 256, 0, stream>>>(xb, qb, xbf, g2 + (long)l * DD, bb2 + (long)l * DD);
    }

    // ================= phase B: cross-attn + feats_proj =================
    ushort_t* vprbf = (ushort_t*)(ws + B_VPRBF);
    ushort_t* pqT   = (ushort_t*)(ws + B_PW);
    ushort_t* pkT   = (ushort_t*)(ws + B_PW + 131072);
    ushort_t* pvT   = (ushort_t*)(ws + B_PW + 262144);
    ushort_t* acbf  = (ushort_t*)(ws + B_ACBF);
    ushort_t* Qpbf  = (ushort_t*)(ws + B_QPBF);
    ushort_t* Kpbf  = (ushort_t*)(ws + B_KPBF);
    float*    Vp    = ws + B_VP;
    ushort_t* VpT   = (ushort_t*)(ws + B_VPT);
    ushort_t* scbf  = (ushort_t*)(ws + B_SC);
    ushort_t* updbf = (ushort_t*)(ws + B_UPD);

    add_f2b_k<<<1024, 256, 0, stream>>>(vid, xb, vprbf, nBTD);   // vproj (bf16)
    f2b_t_k<<<dim3(16, 16, 1), tblk, 0, stream>>>(pqW, pqT, DD, DD, 0, 0);
    f2b_t_k<<<dim3(16, 16, 1), tblk, 0, stream>>>(pkW, pkT, DD, DD, 0, 0);
    f2b_t_k<<<dim3(16, 16, 1), tblk, 0, stream>>>(pvW, pvT, DD, DD, 0, 0);
    f2b_k<<<512, 256, 0, stream>>>(actn_concepts, acbf, (long)NW * DD);

    launch_bgemm(0, 1, acbf, DD, 0, 0, pqT, DD, 0, 0, Qpbf, DD, 0, 0,
                 pqb, NW, DD, DD, 1.f, 1, 1, 1, 0, 0, zbuf, stream);
    launch_bgemm(0, 1, vprbf, DD, 0, 0, pkT, DD, 0, 0, Kpbf, DD, 0, 0,
                 pkb, BB * TT, DD, DD, 1.f, 1, 1, 1, 0, 0, zbuf, stream);
    launch_bgemm(0, 0, vprbf, DD, 0, 0, pvT, DD, 0, 0, Vp, DD, 0, 0,
                 pvb, BB * TT, DD, DD, 1.f, 1, 1, 1, 0, 0, zbuf, stream);
    f2b_t_k<<<dim3(16, 4, 32), tblk, 0, stream>>>(Vp, VpT, TT, DD, (long)TT * DD, (long)TT * DD);

    const int CHUNK = 500;
    for (int c = 0; c < NW / CHUNK; c++) {
        int n0 = c * CHUNK;
        launch_bgemm(0, 1, Qpbf + (long)n0 * DD, DD, 0, 64,
                     Kpbf, DD, (long)TT * DD, 64,
                     scbf, TT, (long)HH * CHUNK * TT, (long)CHUNK * TT,
                     nullptr, CHUNK, TT, HD, 0.125f, HH, BB * HH, 1, 0, 0, zbuf, stream);
        softmax128_bf_k<<<(BB * HH * CHUNK + 3) / 4, 256, 0, stream>>>(scbf, (long)BB * HH * CHUNK);
        launch_bgemm(0, 1, scbf, TT, (long)HH * CHUNK * TT, (long)CHUNK * TT,
                     VpT, TT, (long)DD * TT, (long)HD * TT,
                     updbf, DD, (long)CHUNK * DD, 64,
                     nullptr, CHUNK, HD, TT, 1.f, HH, BB * HH, 1, 0, 0, zbuf, stream);
        launch_bgemm(0, 0, vprbf, DD, (long)TT * DD, 0,
                     updbf, DD, (long)CHUNK * DD, 0,
                     fp_out + n0, NW, (long)TT * NW, 0,
                     nullptr, TT, CHUNK, DD, 1.f, 1, BB, 1, 0, 0, zbuf, stream);
    }

    // ================= phase C: conv tower =================
    ushort_t* fpp = (ushort_t*)(ws + C_FPP);
    ushort_t* wk1 = (ushort_t*)(ws + C_WK1);
    ushort_t* wk2 = (ushort_t*)(ws + C_WK2);
    ushort_t* wk3 = (ushort_t*)(ws + C_WK3);
    ushort_t* wk4 = (ushort_t*)(ws + C_WK4);
    ushort_t* h1  = (ushort_t*)(ws + C_H1);
    ushort_t* h2  = (ushort_t*)(ws + C_H2);
    ushort_t* h3  = (ushort_t*)(ws + C_H3);
    ushort_t* h4  = (ushort_t*)(ws + C_H4);

    zero_k<<<4096, 256, 0, stream>>>(ws, C_SEGF);
    repack_bf_k<<<1024, 256, 0, stream>>>(c1w, wk1, 1024, NW);
    repack_bf_k<<<512, 256, 0, stream>>>(c2w, wk2, 512, 1024);
    repack_bf_k<<<256, 256, 0, stream>>>(c3w, wk3, 256, 512);
    repack_bf_k<<<128, 256, 0, stream>>>(c4w, wk4, 128, 256);
    pad_copy_bf_k<<<2048, 256, 0, stream>>>(fp_out, fpp);

    launch_bgemm(1, 1, fpp, NW, (long)130 * NW, 0,
                 wk1, NW, 0, 0,
                 h1 + 1024, 1024, (long)130 * 1024, 0,
                 c1b, TT, 1024, NW, 1.f, 1, BB, 3, NW, (long)1024 * NW, zbuf, stream);
    launch_bgemm(1, 1, h1, 1024, (long)130 * 1024, 0,
                 wk2, 1024, 0, 0,
                 h2 + 512, 512, (long)130 * 512, 0,
                 c2b, TT, 512, 1024, 1.f, 1, BB, 3, 1024, (long)512 * 1024, zbuf, stream);
    launch_bgemm(1, 1, h2, 512, (long)130 * 512, 0,
                 wk3, 512, 0, 0,
                 h3 + 256, 256, (long)130 * 256, 0,
                 c3b, TT, 256, 512, 1.f, 1, BB, 3, 512, (long)256 * 512, zbuf, stream);
    launch_bgemm(1, 1, h3, 256, (long)130 * 256, 0,
                 wk4, 256, 0, 0,
                 h4 + 128, 128, (long)130 * 128, 0,
                 c4b, TT, 128, 256, 1.f, 1, BB, 3, 256, (long)128 * 256, zbuf, stream);
    conv5_bf_k<<<BB, 128, 0, stream>>>(h4, c5w, c5b, fc_out);

    // ================= segment pooling + logits (fp32) =================
    float* segf = ws + C_SEGF;
    seg_pool_k<<<dim3(SS, BB), 128, 0, stream>>>(fc_out, steds, vid, segf);
    launch_gemm(1, 0, 0, segf, DD, 0, 0, actn_feats, DD, 0, 0, al_out, NCC, 0, 0,
                nullptr, BB * SS, NCC, DD, 1.f, 1, 1, stream);
}

// Round 5
// 1560.607 us; speedup vs baseline: 5.7004x; 1.0776x over previous
//
#include <hip/hip_runtime.h>
#include <hip/hip_bf16.h>

// ---------------- constants ----------------
#define BB 32
#define TT 128
#define DD 512
#define NW 2000
#define NCC 200
#define SS 8
#define LL 4
#define HH 8
#define FF 2048
#define HD 64

typedef unsigned short ushort_t;
typedef __attribute__((ext_vector_type(8))) short bhalf8;
typedef __attribute__((ext_vector_type(4))) float floatx4;

__device__ inline ushort_t f2b(float x) {
    union { float f; unsigned int u; } v; v.f = x;
    unsigned int r = (v.u + 0x7FFFu + ((v.u >> 16) & 1u)) >> 16;
    return (ushort_t)r;
}
__device__ inline float b2f(ushort_t u) {
    union { unsigned int u; float f; } v; v.u = ((unsigned int)u) << 16;
    return v.f;
}
__device__ inline void gld16(const ushort_t* g, ushort_t* l) {
    __builtin_amdgcn_global_load_lds(
        (const __attribute__((address_space(1))) void*)g,
        (__attribute__((address_space(3))) void*)l, 16, 0, 0);
}

// ================= bf16 MFMA GEMM (2-phase pipelined, swizzled LDS) =========
// C[M,N] = act( alpha * sum_tap A[M,K] @ B[N,K]^T + bias )
// batch z: zb=z/batchH, zh=z%batchH; offsets sA1*zb+sA2*zh etc (elements).
template<int ACT, int OUTBF>
__global__ __launch_bounds__(256) void bgemm_k(
    const ushort_t* __restrict__ A, int lda, long sA1, long sA2,
    const ushort_t* __restrict__ B, int ldb, long sB1, long sB2,
    void* __restrict__ Cv, int ldc, long sC1, long sC2,
    const float* __restrict__ bias,
    int M, int N, int K, float alpha, int batchH,
    int taps, long tapA, long tapB, const ushort_t* __restrict__ zbuf)
{
    __shared__ __align__(16) ushort_t sm[2][2][128 * 64];  // 64 KiB
    int z = blockIdx.z;
    int zb = z / batchH, zh = z % batchH;
    A += (long)zb * sA1 + (long)zh * sA2;
    B += (long)zb * sB1 + (long)zh * sB2;
    long cOff = (long)zb * sC1 + (long)zh * sC2;
    int m0 = blockIdx.y * 128, n0 = blockIdx.x * 128;
    int tid = threadIdx.x;
    int wid = tid >> 6, lane = tid & 63;
    int wr = wid >> 1, wc = wid & 1;
    int lr = lane & 15, lg = lane >> 4;

    int kSteps = (K + 63) >> 6;
    int nt = taps * kSteps;

    int rsub = lane >> 3;
    int ssub = lane & 7;
    int scol = ((ssub ^ rsub) << 3);      // pre-swizzled logical col (bf16)
    bool aok[4], bok[4];
    const ushort_t* aptr[4];
    const ushort_t* bptr[4];
    #pragma unroll
    for (int i = 0; i < 4; i++) {
        int row = (wid << 5) + (i << 3) + rsub;
        aok[i] = (m0 + row) < M;
        bok[i] = (n0 + row) < N;
        aptr[i] = A + (long)(m0 + row) * lda + scol;
        bptr[i] = B + (long)(n0 + row) * ldb + scol;
    }

    floatx4 acc[4][4];
    #pragma unroll
    for (int i = 0; i < 4; i++)
        #pragma unroll
        for (int j = 0; j < 4; j++)
            acc[i][j] = (floatx4){0.f, 0.f, 0.f, 0.f};

    // prologue
    {
        bool kOk = scol < K;
        #pragma unroll
        for (int i = 0; i < 4; i++) {
            const ushort_t* as = (kOk && aok[i]) ? aptr[i] : zbuf;
            const ushort_t* bs = (kOk && bok[i]) ? bptr[i] : zbuf;
            int lb = ((wid << 5) + (i << 3)) << 6;
            gld16(as, &sm[0][0][lb]);
            gld16(bs, &sm[0][1][lb]);
        }
    }
    __syncthreads();

    int cur = 0;
    int tap_n = 0, k0_n = 0;
    for (int t = 0; t < nt; t++) {
        k0_n += 64;
        if (k0_n >= K) { k0_n = 0; ++tap_n; }
        if (tap_n < taps) {
            bool kOk = (k0_n + scol) < K;
            #pragma unroll
            for (int i = 0; i < 4; i++) {
                const ushort_t* as =
                    (kOk && aok[i]) ? (aptr[i] + (long)tap_n * tapA + k0_n) : zbuf;
                const ushort_t* bs =
                    (kOk && bok[i]) ? (bptr[i] + (long)tap_n * tapB + k0_n) : zbuf;
                int lb = ((wid << 5) + (i << 3)) << 6;
                gld16(as, &sm[cur ^ 1][0][lb]);
                gld16(bs, &sm[cur ^ 1][1][lb]);
            }
        }
        const char* Ab = (const char*)&sm[cur][0][0];
        const char* Bbs = (const char*)&sm[cur][1][0];
        #pragma unroll
        for (int kk = 0; kk < 2; kk++) {
            bhalf8 a_[4], b_[4];
            #pragma unroll
            for (int i = 0; i < 4; i++) {
                int r = wr * 64 + i * 16 + lr;
                int off = (r << 7) + (((kk << 6) + (lg << 4)) ^ ((r & 7) << 4));
                a_[i] = *(const bhalf8*)(Ab + off);
            }
            #pragma unroll
            for (int j = 0; j < 4; j++) {
                int r = wc * 64 + j * 16 + lr;
                int off = (r << 7) + (((kk << 6) + (lg << 4)) ^ ((r & 7) << 4));
                b_[j] = *(const bhalf8*)(Bbs + off);
            }
            #pragma unroll
            for (int i = 0; i < 4; i++)
                #pragma unroll
                for (int j = 0; j < 4; j++)
                    acc[i][j] = __builtin_amdgcn_mfma_f32_16x16x32_bf16(
                        a_[i], b_[j], acc[i][j], 0, 0, 0);
        }
        __syncthreads();
        cur ^= 1;
    }

    // epilogue: C/D layout col=lane&15, row=(lane>>4)*4+reg
    #pragma unroll
    for (int i = 0; i < 4; i++) {
        int gm_base = m0 + wr * 64 + i * 16 + lg * 4;
        #pragma unroll
        for (int j = 0; j < 4; j++) {
            int gn = n0 + wc * 64 + j * 16 + lr;
            if (gn >= N) continue;
            float bv = bias ? bias[gn] : 0.f;
            #pragma unroll
            for (int r = 0; r < 4; r++) {
                int gm = gm_base + r;
                if (gm >= M) continue;
                float v = acc[i][j][r] * alpha + bv;
                if (ACT == 1) v = fmaxf(v, 0.f);
                long idx = cOff + (long)gm * ldc + gn;
                if (OUTBF) ((ushort_t*)Cv)[idx] = f2b(v);
                else       ((float*)Cv)[idx] = v;
            }
        }
    }
}

static void launch_bgemm(int act, int outbf,
                         const ushort_t* A, int lda, long sA1, long sA2,
                         const ushort_t* B, int ldb, long sB1, long sB2,
                         void* C, int ldc, long sC1, long sC2,
                         const float* bias, int M, int N, int K, float alpha,
                         int batchH, int Z, int taps, long tapA, long tapB,
                         const ushort_t* zbuf, hipStream_t st) {
    dim3 grid((N + 127) / 128, (M + 127) / 128, Z), blk(256);
#define BG(A_, O_) bgemm_k<A_, O_><<<grid, blk, 0, st>>>(A, lda, sA1, sA2, B, ldb, sB1, sB2, C, ldc, sC1, sC2, bias, M, N, K, alpha, batchH, taps, tapA, tapB, zbuf)
    if (act) { if (outbf) BG(1, 1); else BG(1, 0); }
    else     { if (outbf) BG(0, 1); else BG(0, 0); }
#undef BG
}

// ================= fp32 tiled GEMM (logits only) =================
template<int TRANSB>
__global__ __launch_bounds__(256) void gemm_k(
    const float* __restrict__ A, int lda,
    const float* __restrict__ B, int ldb,
    float* __restrict__ C, int ldc,
    int M, int N, int K)
{
    __shared__ float As[16][68];
    __shared__ float Bs[16][68];
    int m0 = blockIdx.y * 64, n0 = blockIdx.x * 64;
    int tid = threadIdx.x;
    int tr = tid / 16, tc = tid % 16;
    float acc[4][4] = {};
    for (int k0 = 0; k0 < K; k0 += 16) {
        {
            int ar = tid / 4;
            int ac = (tid % 4) * 4;
            int gm = m0 + ar;
            #pragma unroll
            for (int i = 0; i < 4; i++) {
                int gk = k0 + ac + i;
                As[ac + i][ar] = (gm < M && gk < K) ? A[(long)gm * lda + gk] : 0.f;
            }
        }
        {
            int bn = tid / 4;
            int bk = (tid % 4) * 4;
            int gn = n0 + bn;
            #pragma unroll
            for (int i = 0; i < 4; i++) {
                int gk = k0 + bk + i;
                Bs[bk + i][bn] = (gn < N && gk < K) ? B[(long)gn * ldb + gk] : 0.f;
            }
        }
        __syncthreads();
        #pragma unroll
        for (int kk = 0; kk < 16; kk++) {
            float a[4], b[4];
            #pragma unroll
            for (int i = 0; i < 4; i++) a[i] = As[kk][tr * 4 + i];
            #pragma unroll
            for (int i = 0; i < 4; i++) b[i] = Bs[kk][tc * 4 + i];
            #pragma unroll
            for (int i = 0; i < 4; i++)
                #pragma unroll
                for (int j = 0; j < 4; j++)
                    acc[i][j] += a[i] * b[j];
        }
        __syncthreads();
    }
    #pragma unroll
    for (int i = 0; i < 4; i++) {
        int gm = m0 + tr * 4 + i;
        if (gm >= M) continue;
        #pragma unroll
        for (int j = 0; j < 4; j++) {
            int gn = n0 + tc * 4 + j;
            if (gn >= N) continue;
            C[(long)gm * ldc + gn] = acc[i][j];
        }
    }
}

// ================= conversions =================
__global__ void f2b_k(const float* __restrict__ in, ushort_t* __restrict__ out, long n) {
    long stride = (long)gridDim.x * blockDim.x * 8;
    for (long i = ((long)blockIdx.x * blockDim.x + threadIdx.x) * 8; i < n; i += stride) {
        float4 a = *(const float4*)(in + i);
        float4 b = *(const float4*)(in + i + 4);
        uint4 o;
        o.x = (unsigned)f2b(a.x) | ((unsigned)f2b(a.y) << 16);
        o.y = (unsigned)f2b(a.z) | ((unsigned)f2b(a.w) << 16);
        o.z = (unsigned)f2b(b.x) | ((unsigned)f2b(b.y) << 16);
        o.w = (unsigned)f2b(b.z) | ((unsigned)f2b(b.w) << 16);
        *(uint4*)(out + i) = o;
    }
}
__global__ void add_f2b_k(const float* __restrict__ a, const float* __restrict__ b,
                          ushort_t* __restrict__ out, long n) {
    long stride = (long)gridDim.x * blockDim.x * 8;
    for (long i = ((long)blockIdx.x * blockDim.x + threadIdx.x) * 8; i < n; i += stride) {
        float4 x = *(const float4*)(a + i);
        float4 y = *(const float4*)(b + i);
        float4 x2 = *(const float4*)(a + i + 4);
        float4 y2 = *(const float4*)(b + i + 4);
        uint4 o;
        o.x = (unsigned)f2b(x.x + y.x) | ((unsigned)f2b(x.y + y.y) << 16);
        o.y = (unsigned)f2b(x.z + y.z) | ((unsigned)f2b(x.w + y.w) << 16);
        o.z = (unsigned)f2b(x2.x + y2.x) | ((unsigned)f2b(x2.y + y2.y) << 16);
        o.w = (unsigned)f2b(x2.z + y2.z) | ((unsigned)f2b(x2.w + y2.w) << 16);
        *(uint4*)(out + i) = o;
    }
}
// transpose+convert fp32 (R x C) -> bf16 (C x R), batched over z
__global__ void f2b_t_k(const float* __restrict__ in, ushort_t* __restrict__ out,
                        int R, int C, long inStride, long outStride) {
    __shared__ float tile[32][33];
    int z = blockIdx.z;
    in += (long)z * inStride;
    out += (long)z * outStride;
    int c0 = blockIdx.x * 32, r0 = blockIdx.y * 32;
    int tx = threadIdx.x, ty = threadIdx.y;
    #pragma unroll
    for (int i = 0; i < 32; i += 8) {
        int r = r0 + ty + i, c = c0 + tx;
        tile[ty + i][tx] = (r < R && c < C) ? in[(long)r * C + c] : 0.f;
    }
    __syncthreads();
    #pragma unroll
    for (int i = 0; i < 32; i += 8) {
        int c = c0 + ty + i, r = r0 + tx;
        if (c < C && r < R) out[(long)c * R + r] = f2b(tile[tx][ty + i]);
    }
}
// bf16 transpose: in (R x C, ldin) -> out (C x R), batched over z
__global__ void t_bf_k(const ushort_t* __restrict__ in, ushort_t* __restrict__ out,
                       int R, int C, int ldin, long inStride, long outStride) {
    __shared__ ushort_t tile[32][33];
    int z = blockIdx.z;
    in += (long)z * inStride;
    out += (long)z * outStride;
    int c0 = blockIdx.x * 32, r0 = blockIdx.y * 32;
    int tx = threadIdx.x, ty = threadIdx.y;
    #pragma unroll
    for (int i = 0; i < 32; i += 8) {
        int r = r0 + ty + i, c = c0 + tx;
        if (r < R && c < C) tile[ty + i][tx] = in[(long)r * ldin + c];
    }
    __syncthreads();
    #pragma unroll
    for (int i = 0; i < 32; i += 8) {
        int c = c0 + ty + i, r = r0 + tx;
        if (c < C && r < R) out[(long)c * R + r] = tile[tx][ty + i];
    }
}
__global__ void cat3all_k(float* __restrict__ dst, const float* __restrict__ a,
                          const float* __restrict__ b, const float* __restrict__ c) {
    int i = blockIdx.x * blockDim.x + threadIdx.x;
    if (i >= LL * 1536) return;
    int l = i / 1536, j = i % 1536;
    float v = (j < 512) ? a[l * 512 + j]
            : (j < 1024) ? b[l * 512 + j - 512] : c[l * 512 + j - 1024];
    dst[i] = v;
}

// ---------------- elementwise ----------------
__global__ void addpos_bf_k(const float* __restrict__ a, const float* __restrict__ pos,
                            float* __restrict__ o, ushort_t* __restrict__ obf,
                            long n, long pmod) {
    for (long i = blockIdx.x * (long)blockDim.x + threadIdx.x; i < n;
         i += (long)gridDim.x * blockDim.x) {
        float v = a[i] + pos[i % pmod];
        o[i] = v;
        obf[i] = f2b(v);
    }
}
__global__ void zero_k(float* __restrict__ p, long n) {
    for (long i = blockIdx.x * (long)blockDim.x + threadIdx.x; i < n;
         i += (long)gridDim.x * blockDim.x)
        p[i] = 0.f;
}
__global__ void sentinel_k(float* p) { p[0] = 1e9f; }

// ---------------- residual + layernorm ----------------
__global__ __launch_bounds__(256) void ln_res_k(float* __restrict__ x,
                                                const float* __restrict__ z,
                                                ushort_t* __restrict__ xbf,
                                                const float* __restrict__ g,
                                                const float* __restrict__ b) {
    long row = blockIdx.x;
    float* px = x + row * DD;
    const float* pz = z + row * DD;
    ushort_t* pb = xbf + row * DD;
    int t = threadIdx.x;
    float v0 = px[t] + pz[t];
    float v1 = px[t + 256] + pz[t + 256];
    float s = v0 + v1, sq = v0 * v0 + v1 * v1;
    for (int o = 32; o > 0; o >>= 1) {
        s += __shfl_xor(s, o, 64);
        sq += __shfl_xor(sq, o, 64);
    }
    __shared__ float ss[4], sqq[4];
    int wave = t >> 6, lane = t & 63;
    if (lane == 0) { ss[wave] = s; sqq[wave] = sq; }
    __syncthreads();
    s = ss[0] + ss[1] + ss[2] + ss[3];
    sq = sqq[0] + sqq[1] + sqq[2] + sqq[3];
    float mean = s * (1.f / DD);
    float var = sq * (1.f / DD) - mean * mean;
    float rstd = 1.f / sqrtf(var + 1e-5f);
    float o0 = (v0 - mean) * rstd * g[t] + b[t];
    float o1 = (v1 - mean) * rstd * g[t + 256] + b[t + 256];
    px[t] = o0;
    px[t + 256] = o1;
    pb[t] = f2b(o0);
    pb[t + 256] = f2b(o1);
}

// ---------------- softmax over bf16 rows of length 128 (in place) ----------
__global__ __launch_bounds__(256) void softmax128_bf_k(ushort_t* __restrict__ s, long nrows) {
    int wave = threadIdx.x >> 6, lane = threadIdx.x & 63;
    long row = (long)blockIdx.x * 4 + wave;
    if (row >= nrows) return;
    ushort_t* p = s + row * 128;
    float a0 = b2f(p[lane]), a1 = b2f(p[lane + 64]);
    float m = fmaxf(a0, a1);
    for (int o = 32; o > 0; o >>= 1) m = fmaxf(m, __shfl_xor(m, o, 64));
    float e0 = expf(a0 - m), e1 = expf(a1 - m);
    float sum = e0 + e1;
    for (int o = 32; o > 0; o >>= 1) sum += __shfl_xor(sum, o, 64);
    float inv = 1.f / sum;
    p[lane] = f2b(e0 * inv);
    p[lane + 64] = f2b(e1 * inv);
}

// ---------------- conv helpers ----------------
__global__ void pad_copy_bf_k(const float* __restrict__ fp, ushort_t* __restrict__ fpp) {
    long total = (long)BB * TT * NW;
    for (long i = blockIdx.x * (long)blockDim.x + threadIdx.x; i < total;
         i += (long)gridDim.x * blockDim.x) {
        long ci = i % NW;
        long r = i / NW;
        long t = r % TT;
        long b = r / TT;
        fpp[(b * 130 + t + 1) * NW + ci] = f2b(fp[i]);
    }
}
__global__ void repack_bf_k(const float* __restrict__ w, ushort_t* __restrict__ wk,
                            int CO, int CI) {
    long total = (long)CO * CI * 3;
    for (long i = blockIdx.x * (long)blockDim.x + threadIdx.x; i < total;
         i += (long)gridDim.x * blockDim.x) {
        long kt = i % 3;
        long r = i / 3;
        long ci = r % CI;
        long co = r / CI;
        wk[kt * (long)CO * CI + co * CI + ci] = f2b(w[i]);
    }
}
// partials reduce: h[b][1+t][co] = bf16(relu(p0+p1+p2+bias[co]))
__global__ void creduce_k(const float* __restrict__ p, const float* __restrict__ bias,
                          ushort_t* __restrict__ out, long plane, int CO) {
    for (long i = blockIdx.x * (long)blockDim.x + threadIdx.x; i < plane;
         i += (long)gridDim.x * blockDim.x) {
        int co = (int)(i % CO);
        long r = i / CO;
        long t = r % TT;
        long b = r / TT;
        float v = p[i] + p[i + plane] + p[i + 2 * plane] + bias[co];
        v = fmaxf(v, 0.f);
        out[(b * 130 + t + 1) * CO + co] = f2b(v);
    }
}
__global__ __launch_bounds__(128) void conv5_bf_k(const ushort_t* __restrict__ h4,
                                                  const float* __restrict__ w,
                                                  const float* __restrict__ bias,
                                                  float* __restrict__ out) {
    int b = blockIdx.x, t = threadIdx.x;
    __shared__ float wsm[384];
    wsm[t] = w[t];
    wsm[t + 128] = w[t + 128];
    wsm[t + 256] = w[t + 256];
    __syncthreads();
    const ushort_t* hb = h4 + (long)b * 130 * 128;
    float acc = bias[0];
    for (int ci = 0; ci < 128; ci++) {
        float w0 = wsm[ci * 3], w1 = wsm[ci * 3 + 1], w2 = wsm[ci * 3 + 2];
        acc += w0 * b2f(hb[(t + 0) * 128 + ci]) + w1 * b2f(hb[(t + 1) * 128 + ci]) +
               w2 * b2f(hb[(t + 2) * 128 + ci]);
    }
    out[b * TT + t] = 1.f / (1.f + expf(-acc));
}

// ---------------- masked segment softmax pooling ----------------
__global__ __launch_bounds__(128) void seg_pool_k(const float* __restrict__ weights,
                                                  const int* __restrict__ steds,
                                                  const float* __restrict__ vid,
                                                  float* __restrict__ segf) {
    int b = blockIdx.y, sidx = blockIdx.x;
    int st = steds[(b * SS + sidx) * 2];
    int ed = steds[(b * SS + sidx) * 2 + 1];
    int t = threadIdx.x;
    float w = (t >= st && t <= ed) ? weights[b * TT + t] : -1e30f;
    __shared__ float red[2];
    __shared__ float aw[TT];
    int wave = t >> 6, lane = t & 63;
    float m = w;
    for (int o = 32; o > 0; o >>= 1) m = fmaxf(m, __shfl_xor(m, o, 64));
    if (lane == 0) red[wave] = m;
    __syncthreads();
    m = fmaxf(red[0], red[1]);
    float e = expf(w - m);
    float sum = e;
    for (int o = 32; o > 0; o >>= 1) sum += __shfl_xor(sum, o, 64);
    __syncthreads();
    if (lane == 0) red[wave] = sum;
    __syncthreads();
    sum = red[0] + red[1];
    aw[t] = e / sum;
    __syncthreads();
    #pragma unroll
    for (int i = 0; i < 4; i++) {
        int d = t + i * 128;
        float acc = 0.f;
        for (int tt = 0; tt < TT; tt++)
            acc += aw[tt] * vid[((long)b * TT + tt) * DD + d];
        segf[((long)b * SS + sidx) * DD + d] = acc;
    }
}

extern "C" void kernel_launch(void* const* d_in, const int* in_sizes, int n_in,
                              void* d_out, int out_size, void* d_ws, size_t ws_size,
                              hipStream_t stream) {
    const float* vid = (const float*)d_in[0];
    const float* actn_feats = (const float*)d_in[2];
    const float* actn_concepts = (const float*)d_in[3];
    const float* pos = (const float*)d_in[4];
    const float* Wq = (const float*)d_in[5];
    const float* bq = (const float*)d_in[6];
    const float* Wk = (const float*)d_in[7];
    const float* bk = (const float*)d_in[8];
    const float* Wv = (const float*)d_in[9];
    const float* bv = (const float*)d_in[10];
    const float* Wo = (const float*)d_in[11];
    const float* bo = (const float*)d_in[12];
    const float* W1 = (const float*)d_in[13];
    const float* b1 = (const float*)d_in[14];
    const float* W2 = (const float*)d_in[15];
    const float* b2 = (const float*)d_in[16];
    const float* g1 = (const float*)d_in[17];
    const float* bb1 = (const float*)d_in[18];
    const float* g2 = (const float*)d_in[19];
    const float* bb2 = (const float*)d_in[20];
    const float* pqW = (const float*)d_in[21];
    const float* pqb = (const float*)d_in[22];
    const float* pkW = (const float*)d_in[23];
    const float* pkb = (const float*)d_in[24];
    const float* pvW = (const float*)d_in[25];
    const float* pvb = (const float*)d_in[26];
    const float* c1w = (const float*)d_in[27];
    const float* c1b = (const float*)d_in[28];
    const float* c2w = (const float*)d_in[29];
    const float* c2b = (const float*)d_in[30];
    const float* c3w = (const float*)d_in[31];
    const float* c3b = (const float*)d_in[32];
    const float* c4w = (const float*)d_in[33];
    const float* c4b = (const float*)d_in[34];
    const float* c5w = (const float*)d_in[35];
    const float* c5b = (const float*)d_in[36];
    const int* steds = (const int*)d_in[37];

    float* out = (float*)d_out;
    float* fc_out = out;            // 32*128
    float* al_out = out + 4096;     // 32*8*200
    float* fp_out = out + 55296;    // 32*128*2000

    float* ws = (float*)d_ws;
    const long NEED = 25165824;  // floats (96 MiB) — proven available
    if (ws_size < (size_t)NEED * 4) {
        sentinel_k<<<1, 1, 0, stream>>>(fc_out);
        return;
    }

    // ---- arena (float-unit offsets) ----
    // phase A:
    const long A_XBF   = 0;          // x bf16 (1,048,576)
    const long A_QKVBF = 1048576;    // qkv bf16 (3,145,728) -> 4,194,304
    const long A_VT    = 4194304;    // vT bf16 (1,048,576) -> 5,242,880
    const long A_SC    = 5242880;    // scores bf16 (2,097,152) -> 7,340,032
    const long A_FFH   = 7340032;    // ffh bf16 (4,194,304) -> 11,534,336
    const long A_AOBF  = 11534336;   // attn out bf16 (1,048,576) -> 12,582,912
    const long A_QB    = 12582912;   // fp32 scratch (2,097,152) -> 14,680,064
    const long A_QKVT  = 14680064;   // qkvT all layers -> 16,252,928
    const long A_WOT   = 16252928;   // -> 16,777,216
    const long A_W1T   = 16777216;   // -> 18,874,368
    const long A_W2T   = 18874368;   // -> 20,971,520
    const long A_QKVB  = 20971520;   // -> 20,977,664
    const long XB      = 21000192;   // x fp32 -> 23,097,344
    // phase B:
    const long B_VPRBF = 2097152;
    const long B_PW    = 3145728;
    const long B_ACBF  = 3538944;
    const long B_QPBF  = 4050944;
    const long B_KPBF  = 4562944;
    const long B_VP    = 5611520;
    const long B_VPT   = 7708672;
    const long B_SC    = 8757248;    // scores bf16 chunk (8,192,000) -> 16,949,248
    const long B_UPD   = 16949248;   // upd bf16 PAIR (8,192,000) -> 25,141,248
    // phase C:
    const long C_FPP   = 0;
    const long C_WK1   = 4160000;
    const long C_WK2   = 7232000;
    const long C_WK3   = 8018432;
    const long C_WK4   = 8215040;
    const long C_H1    = 8264192;
    const long C_H2    = 10394112;
    const long C_H3    = 11459072;
    const long C_H4    = 11991552;
    const long C_SEGF  = 12257792;   // -> 12,388,864
    const long C_PBUF  = 12390400;   // conv partials fp32 (max 12,582,912) -> 24,973,312
    const long ZPAD    = 25165760;   // zbuf (64 floats), never overwritten

    float* xb = ws + XB;
    const ushort_t* zbuf = (const ushort_t*)(ws + ZPAD);
    const long nBTD = (long)BB * TT * DD;

    zero_k<<<1, 64, 0, stream>>>(ws + ZPAD, 64);

    ushort_t* xbf = (ushort_t*)(ws + A_XBF);
    addpos_bf_k<<<2048, 256, 0, stream>>>(vid, pos, xb, xbf, nBTD, (long)TT * DD);

    // ---- all-layer weight prep ----
    ushort_t* qkvT = (ushort_t*)(ws + A_QKVT);
    ushort_t* WoT  = (ushort_t*)(ws + A_WOT);
    ushort_t* W1T  = (ushort_t*)(ws + A_W1T);
    ushort_t* W2T  = (ushort_t*)(ws + A_W2T);
    float*    qkvb = ws + A_QKVB;
    dim3 tblk(32, 8);
    f2b_t_k<<<dim3(16, 16, LL), tblk, 0, stream>>>(Wq, qkvT, DD, DD, (long)DD * DD, 786432);
    f2b_t_k<<<dim3(16, 16, LL), tblk, 0, stream>>>(Wk, qkvT + 262144, DD, DD, (long)DD * DD, 786432);
    f2b_t_k<<<dim3(16, 16, LL), tblk, 0, stream>>>(Wv, qkvT + 524288, DD, DD, (long)DD * DD, 786432);
    f2b_t_k<<<dim3(16, 16, LL), tblk, 0, stream>>>(Wo, WoT, DD, DD, (long)DD * DD, 262144);
    f2b_t_k<<<dim3(64, 16, LL), tblk, 0, stream>>>(W1, W1T, DD, FF, (long)DD * FF, 1048576);
    f2b_t_k<<<dim3(16, 64, LL), tblk, 0, stream>>>(W2, W2T, FF, DD, (long)FF * DD, 1048576);
    cat3all_k<<<(LL * 1536 + 255) / 256, 256, 0, stream>>>(qkvb, bq, bk, bv);

    // ================= phase A: transformer (all-bf16 MFMA) =================
    ushort_t* qkvbf = (ushort_t*)(ws + A_QKVBF);
    ushort_t* vTb   = (ushort_t*)(ws + A_VT);
    ushort_t* scb   = (ushort_t*)(ws + A_SC);
    ushort_t* ffhbf = (ushort_t*)(ws + A_FFH);
    ushort_t* aobf  = (ushort_t*)(ws + A_AOBF);
    float*    qb    = ws + A_QB;

    for (int l = 0; l < LL; l++) {
        // fused QKV projection -> bf16
        launch_bgemm(0, 1, xbf, DD, 0, 0, qkvT + (long)l * 786432, DD, 0, 0,
                     qkvbf, 1536, 0, 0, qkvb + (long)l * 1536,
                     BB * TT, 1536, DD, 1.f, 1, 1, 1, 0, 0, zbuf, stream);
        // vT[b][d][t] = v[b][t][d]
        t_bf_k<<<dim3(16, 4, BB), tblk, 0, stream>>>(qkvbf + 1024, vTb, TT, DD, 1536,
                                                     (long)TT * 1536, (long)DD * TT);
        // scores[b,h,q,t] = q.k/8 (bf16)
        launch_bgemm(0, 1, qkvbf, 1536, (long)TT * 1536, 64,
                     qkvbf + 512, 1536, (long)TT * 1536, 64,
                     scb, TT, (long)HH * TT * TT, (long)TT * TT,
                     nullptr, TT, TT, HD, 0.125f, HH, BB * HH, 1, 0, 0, zbuf, stream);
        softmax128_bf_k<<<(BB * HH * TT) / 4, 256, 0, stream>>>(scb, (long)BB * HH * TT);
        // PV: aobf[b,q,h*64+d] = P . vT
        launch_bgemm(0, 1, scb, TT, (long)HH * TT * TT, (long)TT * TT,
                     vTb, TT, (long)DD * TT, (long)HD * TT,
                     aobf, DD, (long)TT * DD, 64,
                     nullptr, TT, HD, TT, 1.f, HH, BB * HH, 1, 0, 0, zbuf, stream);
        // output projection
        launch_bgemm(0, 0, aobf, DD, 0, 0, WoT + (long)l * 262144, DD, 0, 0,
                     qb, DD, 0, 0, bo + (long)l * DD,
                     BB * TT, DD, DD, 1.f, 1, 1, 1, 0, 0, zbuf, stream);
        ln_res_k<<<BB * TT, 256, 0, stream>>>(xb, qb, xbf, g1 + (long)l * DD, bb1 + (long)l * DD);
        // FF
        launch_bgemm(1, 1, xbf, DD, 0, 0, W1T + (long)l * 1048576, DD, 0, 0,
                     ffhbf, FF, 0, 0, b1 + (long)l * FF,
                     BB * TT, FF, DD, 1.f, 1, 1, 1, 0, 0, zbuf, stream);
        launch_bgemm(0, 0, ffhbf, FF, 0, 0, W2T + (long)l * 1048576, FF, 0, 0,
                     qb, DD, 0, 0, b2 + (long)l * DD,
                     BB * TT, DD, FF, 1.f, 1, 1, 1, 0, 0, zbuf, stream);
        ln_res_k<<<BB * TT, 256, 0, stream>>>(xb, qb, xbf, g2 + (long)l * DD, bb2 + (long)l * DD);
    }

    // ================= phase B: cross-attn + feats_proj =================
    ushort_t* vprbf = (ushort_t*)(ws + B_VPRBF);
    ushort_t* pqT   = (ushort_t*)(ws + B_PW);
    ushort_t* pkT   = (ushort_t*)(ws + B_PW + 131072);
    ushort_t* pvT   = (ushort_t*)(ws + B_PW + 262144);
    ushort_t* acbf  = (ushort_t*)(ws + B_ACBF);
    ushort_t* Qpbf  = (ushort_t*)(ws + B_QPBF);
    ushort_t* Kpbf  = (ushort_t*)(ws + B_KPBF);
    float*    Vp    = ws + B_VP;
    ushort_t* VpT   = (ushort_t*)(ws + B_VPT);
    ushort_t* scbf  = (ushort_t*)(ws + B_SC);
    ushort_t* updbf = (ushort_t*)(ws + B_UPD);

    add_f2b_k<<<1024, 256, 0, stream>>>(vid, xb, vprbf, nBTD);
    f2b_t_k<<<dim3(16, 16, 1), tblk, 0, stream>>>(pqW, pqT, DD, DD, 0, 0);
    f2b_t_k<<<dim3(16, 16, 1), tblk, 0, stream>>>(pkW, pkT, DD, DD, 0, 0);
    f2b_t_k<<<dim3(16, 16, 1), tblk, 0, stream>>>(pvW, pvT, DD, DD, 0, 0);
    f2b_k<<<512, 256, 0, stream>>>(actn_concepts, acbf, (long)NW * DD);

    launch_bgemm(0, 1, acbf, DD, 0, 0, pqT, DD, 0, 0, Qpbf, DD, 0, 0,
                 pqb, NW, DD, DD, 1.f, 1, 1, 1, 0, 0, zbuf, stream);
    launch_bgemm(0, 1, vprbf, DD, 0, 0, pkT, DD, 0, 0, Kpbf, DD, 0, 0,
                 pkb, BB * TT, DD, DD, 1.f, 1, 1, 1, 0, 0, zbuf, stream);
    launch_bgemm(0, 0, vprbf, DD, 0, 0, pvT, DD, 0, 0, Vp, DD, 0, 0,
                 pvb, BB * TT, DD, DD, 1.f, 1, 1, 1, 0, 0, zbuf, stream);
    f2b_t_k<<<dim3(16, 4, BB), tblk, 0, stream>>>(Vp, VpT, TT, DD, (long)TT * DD, (long)TT * DD);

    const int CHUNK = 500;
    for (int c = 0; c < NW / CHUNK; c++) {
        int n0 = c * CHUNK;
        launch_bgemm(0, 1, Qpbf + (long)n0 * DD, DD, 0, 64,
                     Kpbf, DD, (long)TT * DD, 64,
                     scbf, TT, (long)HH * CHUNK * TT, (long)CHUNK * TT,
                     nullptr, CHUNK, TT, HD, 0.125f, HH, BB * HH, 1, 0, 0, zbuf, stream);
        softmax128_bf_k<<<(BB * HH * CHUNK + 3) / 4, 256, 0, stream>>>(scbf, (long)BB * HH * CHUNK);
        // upd pair layout: per b, 1000 rows; chunk parity selects row block
        launch_bgemm(0, 1, scbf, TT, (long)HH * CHUNK * TT, (long)CHUNK * TT,
                     VpT, TT, (long)DD * TT, (long)HD * TT,
                     updbf + (long)(c & 1) * CHUNK * DD, DD, (long)2 * CHUNK * DD, 64,
                     nullptr, CHUNK, HD, TT, 1.f, HH, BB * HH, 1, 0, 0, zbuf, stream);
        if (c & 1) {
            int p = c >> 1;
            launch_bgemm(0, 0, vprbf, DD, (long)TT * DD, 0,
                         updbf, DD, (long)2 * CHUNK * DD, 0,
                         fp_out + (long)p * 2 * CHUNK, NW, (long)TT * NW, 0,
                         nullptr, TT, 2 * CHUNK, DD, 1.f, 1, BB, 1, 0, 0, zbuf, stream);
        }
    }

    // ================= phase C: conv tower (tap-split, fp32 partials) ======
    ushort_t* fpp = (ushort_t*)(ws + C_FPP);
    ushort_t* wk1 = (ushort_t*)(ws + C_WK1);
    ushort_t* wk2 = (ushort_t*)(ws + C_WK2);
    ushort_t* wk3 = (ushort_t*)(ws + C_WK3);
    ushort_t* wk4 = (ushort_t*)(ws + C_WK4);
    ushort_t* h1  = (ushort_t*)(ws + C_H1);
    ushort_t* h2  = (ushort_t*)(ws + C_H2);
    ushort_t* h3  = (ushort_t*)(ws + C_H3);
    ushort_t* h4  = (ushort_t*)(ws + C_H4);
    float*    pbuf = ws + C_PBUF;

    zero_k<<<4096, 256, 0, stream>>>(ws, C_SEGF);
    repack_bf_k<<<1024, 256, 0, stream>>>(c1w, wk1, 1024, NW);
    repack_bf_k<<<512, 256, 0, stream>>>(c2w, wk2, 512, 1024);
    repack_bf_k<<<256, 256, 0, stream>>>(c3w, wk3, 256, 512);
    repack_bf_k<<<128, 256, 0, stream>>>(c4w, wk4, 128, 256);
    pad_copy_bf_k<<<2048, 256, 0, stream>>>(fp_out, fpp);

    // conv1: z = tap*32 + b (zb=tap via batchH=BB)
    {
        long plane = (long)BB * TT * 1024;
        launch_bgemm(0, 0, fpp, NW, NW, (long)130 * NW,
                     wk1, NW, (long)1024 * NW, 0,
                     pbuf, 1024, plane, (long)TT * 1024,
                     nullptr, TT, 1024, NW, 1.f, BB, 3 * BB, 1, 0, 0, zbuf, stream);
        creduce_k<<<2048, 256, 0, stream>>>(pbuf, c1b, h1, plane, 1024);
    }
    {
        long plane = (long)BB * TT * 512;
        launch_bgemm(0, 0, h1, 1024, 1024, (long)130 * 1024,
                     wk2, 1024, (long)512 * 1024, 0,
                     pbuf, 512, plane, (long)TT * 512,
                     nullptr, TT, 512, 1024, 1.f, BB, 3 * BB, 1, 0, 0, zbuf, stream);
        creduce_k<<<2048, 256, 0, stream>>>(pbuf, c2b, h2, plane, 512);
    }
    {
        long plane = (long)BB * TT * 256;
        launch_bgemm(0, 0, h2, 512, 512, (long)130 * 512,
                     wk3, 512, (long)256 * 512, 0,
                     pbuf, 256, plane, (long)TT * 256,
                     nullptr, TT, 256, 512, 1.f, BB, 3 * BB, 1, 0, 0, zbuf, stream);
        creduce_k<<<1024, 256, 0, stream>>>(pbuf, c3b, h3, plane, 256);
    }
    {
        long plane = (long)BB * TT * 128;
        launch_bgemm(0, 0, h3, 256, 256, (long)130 * 256,
                     wk4, 256, (long)128 * 256, 0,
                     pbuf, 128, plane, (long)TT * 128,
                     nullptr, TT, 128, 256, 1.f, BB, 3 * BB, 1, 0, 0, zbuf, stream);
        creduce_k<<<512, 256, 0, stream>>>(pbuf, c4b, h4, plane, 128);
    }
    conv5_bf_k<<<BB, 128, 0, stream>>>(h4, c5w, c5b, fc_out);

    // ================= segment pooling + logits (fp32) =================
    float* segf = ws + C_SEGF;
    seg_pool_k<<<dim3(SS, BB), 128, 0, stream>>>(fc_out, steds, vid, segf);
    gemm_k<1><<<dim3((NCC + 63) / 64, (BB * SS + 63) / 64, 1), 256, 0, stream>>>(
        segf, DD, actn_feats, DD, al_out, NCC, BB * SS, NCC, DD);
}

// Round 6
// 1235.303 us; speedup vs baseline: 7.2016x; 1.2633x over previous
//
#include <hip/hip_runtime.h>
#include <hip/hip_bf16.h>

// ---------------- constants ----------------
#define BB 32
#define TT 128
#define DD 512
#define NW 2000
#define NCC 200
#define SS 8
#define LL 4
#define HH 8
#define FF 2048
#define HD 64

typedef unsigned short ushort_t;
typedef __attribute__((ext_vector_type(8))) short bhalf8;
typedef __attribute__((ext_vector_type(4))) float floatx4;

__device__ inline ushort_t f2b(float x) {
    union { float f; unsigned int u; } v; v.f = x;
    unsigned int r = (v.u + 0x7FFFu + ((v.u >> 16) & 1u)) >> 16;
    return (ushort_t)r;
}
__device__ inline float b2f(ushort_t u) {
    union { unsigned int u; float f; } v; v.u = ((unsigned int)u) << 16;
    return v.f;
}
__device__ inline void gld16(const ushort_t* g, ushort_t* l) {
    __builtin_amdgcn_global_load_lds(
        (const __attribute__((address_space(1))) void*)g,
        (__attribute__((address_space(3))) void*)l, 16, 0, 0);
}

// ================= bf16 MFMA GEMM (2-phase pipelined, swizzled LDS) =========
// C[M,N] = act( alpha * sum_tap A[M,K] @ B[N,K]^T + bias )
template<int ACT, int OUTBF>
__global__ __launch_bounds__(256) void bgemm_k(
    const ushort_t* __restrict__ A, int lda, long sA1, long sA2,
    const ushort_t* __restrict__ B, int ldb, long sB1, long sB2,
    void* __restrict__ Cv, int ldc, long sC1, long sC2,
    const float* __restrict__ bias,
    int M, int N, int K, float alpha, int batchH,
    int taps, long tapA, long tapB, const ushort_t* __restrict__ zbuf)
{
    __shared__ __align__(16) ushort_t sm[2][2][128 * 64];  // 64 KiB
    int z = blockIdx.z;
    int zb = z / batchH, zh = z % batchH;
    A += (long)zb * sA1 + (long)zh * sA2;
    B += (long)zb * sB1 + (long)zh * sB2;
    long cOff = (long)zb * sC1 + (long)zh * sC2;
    int m0 = blockIdx.y * 128, n0 = blockIdx.x * 128;
    int tid = threadIdx.x;
    int wid = tid >> 6, lane = tid & 63;
    int wr = wid >> 1, wc = wid & 1;
    int lr = lane & 15, lg = lane >> 4;

    int kSteps = (K + 63) >> 6;
    int nt = taps * kSteps;

    int rsub = lane >> 3;
    int ssub = lane & 7;
    int scol = ((ssub ^ rsub) << 3);      // pre-swizzled logical col (bf16)
    bool aok[4], bok[4];
    const ushort_t* aptr[4];
    const ushort_t* bptr[4];
    #pragma unroll
    for (int i = 0; i < 4; i++) {
        int row = (wid << 5) + (i << 3) + rsub;
        aok[i] = (m0 + row) < M;
        bok[i] = (n0 + row) < N;
        aptr[i] = A + (long)(m0 + row) * lda + scol;
        bptr[i] = B + (long)(n0 + row) * ldb + scol;
    }

    floatx4 acc[4][4];
    #pragma unroll
    for (int i = 0; i < 4; i++)
        #pragma unroll
        for (int j = 0; j < 4; j++)
            acc[i][j] = (floatx4){0.f, 0.f, 0.f, 0.f};

    // prologue
    {
        bool kOk = scol < K;
        #pragma unroll
        for (int i = 0; i < 4; i++) {
            const ushort_t* as = (kOk && aok[i]) ? aptr[i] : zbuf;
            const ushort_t* bs = (kOk && bok[i]) ? bptr[i] : zbuf;
            int lb = ((wid << 5) + (i << 3)) << 6;
            gld16(as, &sm[0][0][lb]);
            gld16(bs, &sm[0][1][lb]);
        }
    }
    __syncthreads();

    int cur = 0;
    int tap_n = 0, k0_n = 0;
    for (int t = 0; t < nt; t++) {
        k0_n += 64;
        if (k0_n >= K) { k0_n = 0; ++tap_n; }
        if (tap_n < taps) {
            bool kOk = (k0_n + scol) < K;
            #pragma unroll
            for (int i = 0; i < 4; i++) {
                const ushort_t* as =
                    (kOk && aok[i]) ? (aptr[i] + (long)tap_n * tapA + k0_n) : zbuf;
                const ushort_t* bs =
                    (kOk && bok[i]) ? (bptr[i] + (long)tap_n * tapB + k0_n) : zbuf;
                int lb = ((wid << 5) + (i << 3)) << 6;
                gld16(as, &sm[cur ^ 1][0][lb]);
                gld16(bs, &sm[cur ^ 1][1][lb]);
            }
        }
        const char* Ab = (const char*)&sm[cur][0][0];
        const char* Bbs = (const char*)&sm[cur][1][0];
        #pragma unroll
        for (int kk = 0; kk < 2; kk++) {
            bhalf8 a_[4], b_[4];
            #pragma unroll
            for (int i = 0; i < 4; i++) {
                int r = wr * 64 + i * 16 + lr;
                int off = (r << 7) + (((kk << 6) + (lg << 4)) ^ ((r & 7) << 4));
                a_[i] = *(const bhalf8*)(Ab + off);
            }
            #pragma unroll
            for (int j = 0; j < 4; j++) {
                int r = wc * 64 + j * 16 + lr;
                int off = (r << 7) + (((kk << 6) + (lg << 4)) ^ ((r & 7) << 4));
                b_[j] = *(const bhalf8*)(Bbs + off);
            }
            #pragma unroll
            for (int i = 0; i < 4; i++)
                #pragma unroll
                for (int j = 0; j < 4; j++)
                    acc[i][j] = __builtin_amdgcn_mfma_f32_16x16x32_bf16(
                        a_[i], b_[j], acc[i][j], 0, 0, 0);
        }
        __syncthreads();
        cur ^= 1;
    }

    // epilogue: C/D layout col=lane&15, row=(lane>>4)*4+reg
    #pragma unroll
    for (int i = 0; i < 4; i++) {
        int gm_base = m0 + wr * 64 + i * 16 + lg * 4;
        #pragma unroll
        for (int j = 0; j < 4; j++) {
            int gn = n0 + wc * 64 + j * 16 + lr;
            if (gn >= N) continue;
            float bv = bias ? bias[gn] : 0.f;
            #pragma unroll
            for (int r = 0; r < 4; r++) {
                int gm = gm_base + r;
                if (gm >= M) continue;
                float v = acc[i][j][r] * alpha + bv;
                if (ACT == 1) v = fmaxf(v, 0.f);
                long idx = cOff + (long)gm * ldc + gn;
                if (OUTBF) ((ushort_t*)Cv)[idx] = f2b(v);
                else       ((float*)Cv)[idx] = v;
            }
        }
    }
}

static void launch_bgemm(int act, int outbf,
                         const ushort_t* A, int lda, long sA1, long sA2,
                         const ushort_t* B, int ldb, long sB1, long sB2,
                         void* C, int ldc, long sC1, long sC2,
                         const float* bias, int M, int N, int K, float alpha,
                         int batchH, int Z, int taps, long tapA, long tapB,
                         const ushort_t* zbuf, hipStream_t st) {
    dim3 grid((N + 127) / 128, (M + 127) / 128, Z), blk(256);
#define BG(A_, O_) bgemm_k<A_, O_><<<grid, blk, 0, st>>>(A, lda, sA1, sA2, B, ldb, sB1, sB2, C, ldc, sC1, sC2, bias, M, N, K, alpha, batchH, taps, tapA, tapB, zbuf)
    if (act) { if (outbf) BG(1, 1); else BG(1, 0); }
    else     { if (outbf) BG(0, 1); else BG(0, 0); }
#undef BG
}

// ================= fused attention (QK^T -> softmax -> PV) ==================
// One block per z; z -> c (M-chunk), b, h:  z = (b*H + h)*nc + c.
// Q: rows = queries (ldq), + b*sQb + c*sQc + h*64.   K: 128 rows, + b*sKb + h*64.
// VT: [.., 64 d rows, 128 t] at + b*sVb + h*64*128.  O: + b*sOb + c*sOc + h*64.
// out[q][d] = sum_t softmax_t(Q.K/8)[q][t] * V[t][d]
template<int CHECKQ>
__global__ __launch_bounds__(256) void fattn_k(
    const ushort_t* __restrict__ Q, int ldq, long sQb, long sQc,
    const ushort_t* __restrict__ K, int ldk, long sKb,
    const ushort_t* __restrict__ VT, long sVb,
    ushort_t* __restrict__ O, int ldo, long sOb, long sOc,
    int nc, int Mtot, const ushort_t* __restrict__ zbuf)
{
    __shared__ __align__(16) ushort_t Qs[128 * 64];
    __shared__ __align__(16) ushort_t Ks[128 * 64];
    __shared__ __align__(16) ushort_t Vs[64 * 128];
    __shared__ __align__(16) ushort_t Ps[128 * 128];
    int z = blockIdx.x;
    int c = z % nc, rr_ = z / nc;
    int h = rr_ % HH, b = rr_ / HH;
    int mQ = Mtot - c * 128;                    // valid query rows (>=128 -> full)
    const ushort_t* Qb = Q + (long)b * sQb + (long)c * sQc + h * 64;
    const ushort_t* Kb = K + (long)b * sKb + h * 64;
    const ushort_t* Vb = VT + (long)b * sVb + (long)h * 64 * 128;
    ushort_t* Ob = O + (long)b * sOb + (long)c * sOc + h * 64;

    int tid = threadIdx.x, wid = tid >> 6, lane = tid & 63;
    int lr = lane & 15, lg = lane >> 4;

    // ---- stage Q,K (128x64), VT (64x128) with XOR-swizzled sources ----
    {
        int rsub = lane >> 3, csub = lane & 7;
        #pragma unroll
        for (int i = 0; i < 4; i++) {
            int row = wid * 32 + i * 8 + rsub;
            int cc = (csub ^ rsub) * 8;
            const ushort_t* qs = (!CHECKQ || row < mQ) ? (Qb + (long)row * ldq + cc) : zbuf;
            gld16(qs, &Qs[(wid * 32 + i * 8) * 64]);
            gld16(Kb + (long)row * ldk + cc, &Ks[(wid * 32 + i * 8) * 64]);
        }
        int d4 = lane >> 4, c16 = lane & 15;
        #pragma unroll
        for (int i = 0; i < 4; i++) {
            int d = wid * 16 + i * 4 + d4;
            int cc = (c16 ^ (d & 7)) * 8;
            gld16(Vb + (long)d * 128 + cc, &Vs[(wid * 16 + i * 4) * 128]);
        }
    }
    __syncthreads();

    // ---- QK^T: wave w owns q-rows [w*32, w*32+32) ----
    floatx4 acc[2][8];
    #pragma unroll
    for (int i = 0; i < 2; i++)
        #pragma unroll
        for (int j = 0; j < 8; j++)
            acc[i][j] = (floatx4){0.f, 0.f, 0.f, 0.f};
    const char* Qc = (const char*)Qs;
    const char* Kc = (const char*)Ks;
    #pragma unroll
    for (int kk = 0; kk < 2; kk++) {
        bhalf8 a_[2], b_[8];
        #pragma unroll
        for (int i = 0; i < 2; i++) {
            int r = wid * 32 + i * 16 + lr;
            a_[i] = *(const bhalf8*)(Qc + (r << 7) + ((((kk << 2) + lg) ^ (r & 7)) << 4));
        }
        #pragma unroll
        for (int j = 0; j < 8; j++) {
            int r = j * 16 + lr;
            b_[j] = *(const bhalf8*)(Kc + (r << 7) + ((((kk << 2) + lg) ^ (r & 7)) << 4));
        }
        #pragma unroll
        for (int i = 0; i < 2; i++)
            #pragma unroll
            for (int j = 0; j < 8; j++)
                acc[i][j] = __builtin_amdgcn_mfma_f32_16x16x32_bf16(
                    a_[i], b_[j], acc[i][j], 0, 0, 0);
    }

    // ---- softmax (rows in-register; reduce across 16-lane col group) ----
    #pragma unroll
    for (int i = 0; i < 2; i++) {
        #pragma unroll
        for (int r = 0; r < 4; r++) {
            int row = wid * 32 + i * 16 + lg * 4 + r;
            float v[8], m = -1e30f;
            #pragma unroll
            for (int j = 0; j < 8; j++) { v[j] = acc[i][j][r] * 0.125f; m = fmaxf(m, v[j]); }
            #pragma unroll
            for (int o = 8; o > 0; o >>= 1) m = fmaxf(m, __shfl_xor(m, o, 64));
            float s = 0.f;
            #pragma unroll
            for (int j = 0; j < 8; j++) { v[j] = expf(v[j] - m); s += v[j]; }
            #pragma unroll
            for (int o = 8; o > 0; o >>= 1) s += __shfl_xor(s, o, 64);
            float inv = 1.f / s;
            #pragma unroll
            for (int j = 0; j < 8; j++) {
                int col = j * 16 + lr;
                int byte = (row << 8) + ((((col >> 3) ^ (row & 7)) << 4)) + ((col & 7) << 1);
                *(ushort_t*)((char*)Ps + byte) = f2b(v[j] * inv);
            }
        }
    }
    __syncthreads();

    // ---- PV: out rows = q-rows, cols = 64 d ----
    floatx4 acc2[2][4];
    #pragma unroll
    for (int i = 0; i < 2; i++)
        #pragma unroll
        for (int j = 0; j < 4; j++)
            acc2[i][j] = (floatx4){0.f, 0.f, 0.f, 0.f};
    const char* Pc = (const char*)Ps;
    const char* Vc = (const char*)Vs;
    #pragma unroll
    for (int kk = 0; kk < 4; kk++) {
        bhalf8 a_[2], b_[4];
        #pragma unroll
        for (int i = 0; i < 2; i++) {
            int r = wid * 32 + i * 16 + lr;
            a_[i] = *(const bhalf8*)(Pc + (r << 8) + ((((kk << 2) + lg) ^ (r & 7)) << 4));
        }
        #pragma unroll
        for (int j = 0; j < 4; j++) {
            int d = j * 16 + lr;
            b_[j] = *(const bhalf8*)(Vc + (d << 8) + ((((kk << 2) + lg) ^ (d & 7)) << 4));
        }
        #pragma unroll
        for (int i = 0; i < 2; i++)
            #pragma unroll
            for (int j = 0; j < 4; j++)
                acc2[i][j] = __builtin_amdgcn_mfma_f32_16x16x32_bf16(
                    a_[i], b_[j], acc2[i][j], 0, 0, 0);
    }
    #pragma unroll
    for (int i = 0; i < 2; i++) {
        #pragma unroll
        for (int r = 0; r < 4; r++) {
            int q = wid * 32 + i * 16 + lg * 4 + r;
            if (CHECKQ && q >= mQ) continue;
            #pragma unroll
            for (int j = 0; j < 4; j++) {
                int d = j * 16 + lr;
                Ob[(long)q * ldo + d] = f2b(acc2[i][j][r]);
            }
        }
    }
}

// ================= fp32 tiled GEMM (logits only) =================
template<int TRANSB>
__global__ __launch_bounds__(256) void gemm_k(
    const float* __restrict__ A, int lda,
    const float* __restrict__ B, int ldb,
    float* __restrict__ C, int ldc,
    int M, int N, int K)
{
    __shared__ float As[16][68];
    __shared__ float Bs[16][68];
    int m0 = blockIdx.y * 64, n0 = blockIdx.x * 64;
    int tid = threadIdx.x;
    int tr = tid / 16, tc = tid % 16;
    float acc[4][4] = {};
    for (int k0 = 0; k0 < K; k0 += 16) {
        {
            int ar = tid / 4;
            int ac = (tid % 4) * 4;
            int gm = m0 + ar;
            #pragma unroll
            for (int i = 0; i < 4; i++) {
                int gk = k0 + ac + i;
                As[ac + i][ar] = (gm < M && gk < K) ? A[(long)gm * lda + gk] : 0.f;
            }
        }
        {
            int bn = tid / 4;
            int bk = (tid % 4) * 4;
            int gn = n0 + bn;
            #pragma unroll
            for (int i = 0; i < 4; i++) {
                int gk = k0 + bk + i;
                Bs[bk + i][bn] = (gn < N && gk < K) ? B[(long)gn * ldb + gk] : 0.f;
            }
        }
        __syncthreads();
        #pragma unroll
        for (int kk = 0; kk < 16; kk++) {
            float a[4], b[4];
            #pragma unroll
            for (int i = 0; i < 4; i++) a[i] = As[kk][tr * 4 + i];
            #pragma unroll
            for (int i = 0; i < 4; i++) b[i] = Bs[kk][tc * 4 + i];
            #pragma unroll
            for (int i = 0; i < 4; i++)
                #pragma unroll
                for (int j = 0; j < 4; j++)
                    acc[i][j] += a[i] * b[j];
        }
        __syncthreads();
    }
    #pragma unroll
    for (int i = 0; i < 4; i++) {
        int gm = m0 + tr * 4 + i;
        if (gm >= M) continue;
        #pragma unroll
        for (int j = 0; j < 4; j++) {
            int gn = n0 + tc * 4 + j;
            if (gn >= N) continue;
            C[(long)gm * ldc + gn] = acc[i][j];
        }
    }
}

// ================= conversions =================
__global__ void f2b_k(const float* __restrict__ in, ushort_t* __restrict__ out, long n) {
    long stride = (long)gridDim.x * blockDim.x * 8;
    for (long i = ((long)blockIdx.x * blockDim.x + threadIdx.x) * 8; i < n; i += stride) {
        float4 a = *(const float4*)(in + i);
        float4 b = *(const float4*)(in + i + 4);
        uint4 o;
        o.x = (unsigned)f2b(a.x) | ((unsigned)f2b(a.y) << 16);
        o.y = (unsigned)f2b(a.z) | ((unsigned)f2b(a.w) << 16);
        o.z = (unsigned)f2b(b.x) | ((unsigned)f2b(b.y) << 16);
        o.w = (unsigned)f2b(b.z) | ((unsigned)f2b(b.w) << 16);
        *(uint4*)(out + i) = o;
    }
}
__global__ void add_f2b_k(const float* __restrict__ a, const float* __restrict__ b,
                          ushort_t* __restrict__ out, long n) {
    long stride = (long)gridDim.x * blockDim.x * 8;
    for (long i = ((long)blockIdx.x * blockDim.x + threadIdx.x) * 8; i < n; i += stride) {
        float4 x = *(const float4*)(a + i);
        float4 y = *(const float4*)(b + i);
        float4 x2 = *(const float4*)(a + i + 4);
        float4 y2 = *(const float4*)(b + i + 4);
        uint4 o;
        o.x = (unsigned)f2b(x.x + y.x) | ((unsigned)f2b(x.y + y.y) << 16);
        o.y = (unsigned)f2b(x.z + y.z) | ((unsigned)f2b(x.w + y.w) << 16);
        o.z = (unsigned)f2b(x2.x + y2.x) | ((unsigned)f2b(x2.y + y2.y) << 16);
        o.w = (unsigned)f2b(x2.z + y2.z) | ((unsigned)f2b(x2.w + y2.w) << 16);
        *(uint4*)(out + i) = o;
    }
}
__global__ void f2b_t_k(const float* __restrict__ in, ushort_t* __restrict__ out,
                        int R, int C, long inStride, long outStride) {
    __shared__ float tile[32][33];
    int z = blockIdx.z;
    in += (long)z * inStride;
    out += (long)z * outStride;
    int c0 = blockIdx.x * 32, r0 = blockIdx.y * 32;
    int tx = threadIdx.x, ty = threadIdx.y;
    #pragma unroll
    for (int i = 0; i < 32; i += 8) {
        int r = r0 + ty + i, c = c0 + tx;
        tile[ty + i][tx] = (r < R && c < C) ? in[(long)r * C + c] : 0.f;
    }
    __syncthreads();
    #pragma unroll
    for (int i = 0; i < 32; i += 8) {
        int c = c0 + ty + i, r = r0 + tx;
        if (c < C && r < R) out[(long)c * R + r] = f2b(tile[tx][ty + i]);
    }
}
__global__ void t_bf_k(const ushort_t* __restrict__ in, ushort_t* __restrict__ out,
                       int R, int C, int ldin, long inStride, long outStride) {
    __shared__ ushort_t tile[32][33];
    int z = blockIdx.z;
    in += (long)z * inStride;
    out += (long)z * outStride;
    int c0 = blockIdx.x * 32, r0 = blockIdx.y * 32;
    int tx = threadIdx.x, ty = threadIdx.y;
    #pragma unroll
    for (int i = 0; i < 32; i += 8) {
        int r = r0 + ty + i, c = c0 + tx;
        if (r < R && c < C) tile[ty + i][tx] = in[(long)r * ldin + c];
    }
    __syncthreads();
    #pragma unroll
    for (int i = 0; i < 32; i += 8) {
        int c = c0 + ty + i, r = r0 + tx;
        if (c < C && r < R) out[(long)c * R + r] = tile[tx][ty + i];
    }
}
__global__ void cat3all_k(float* __restrict__ dst, const float* __restrict__ a,
                          const float* __restrict__ b, const float* __restrict__ c) {
    int i = blockIdx.x * blockDim.x + threadIdx.x;
    if (i >= LL * 1536) return;
    int l = i / 1536, j = i % 1536;
    float v = (j < 512) ? a[l * 512 + j]
            : (j < 1024) ? b[l * 512 + j - 512] : c[l * 512 + j - 1024];
    dst[i] = v;
}

// ---------------- elementwise ----------------
__global__ void addpos_bf_k(const float* __restrict__ a, const float* __restrict__ pos,
                            float* __restrict__ o, ushort_t* __restrict__ obf,
                            long n, long pmod) {
    for (long i = blockIdx.x * (long)blockDim.x + threadIdx.x; i < n;
         i += (long)gridDim.x * blockDim.x) {
        float v = a[i] + pos[i % pmod];
        o[i] = v;
        obf[i] = f2b(v);
    }
}
__global__ void zero_k(float* __restrict__ p, long n) {
    for (long i = blockIdx.x * (long)blockDim.x + threadIdx.x; i < n;
         i += (long)gridDim.x * blockDim.x)
        p[i] = 0.f;
}
__global__ void sentinel_k(float* p) { p[0] = 1e9f; }
// zero pad rows r=0 and r=129 of a (B,130,CO) channel-last buffer
__global__ void padzero_k(ushort_t* __restrict__ h, int CO) {
    int b = blockIdx.x;
    for (int i = threadIdx.x; i < CO; i += blockDim.x) {
        h[(long)b * 130 * CO + i] = 0;
        h[((long)b * 130 + 129) * CO + i] = 0;
    }
}

// ---------------- residual + layernorm ----------------
__global__ __launch_bounds__(256) void ln_res_k(float* __restrict__ x,
                                                const float* __restrict__ z,
                                                ushort_t* __restrict__ xbf,
                                                const float* __restrict__ g,
                                                const float* __restrict__ b) {
    long row = blockIdx.x;
    float* px = x + row * DD;
    const float* pz = z + row * DD;
    ushort_t* pb = xbf + row * DD;
    int t = threadIdx.x;
    float v0 = px[t] + pz[t];
    float v1 = px[t + 256] + pz[t + 256];
    float s = v0 + v1, sq = v0 * v0 + v1 * v1;
    for (int o = 32; o > 0; o >>= 1) {
        s += __shfl_xor(s, o, 64);
        sq += __shfl_xor(sq, o, 64);
    }
    __shared__ float ss[4], sqq[4];
    int wave = t >> 6, lane = t & 63;
    if (lane == 0) { ss[wave] = s; sqq[wave] = sq; }
    __syncthreads();
    s = ss[0] + ss[1] + ss[2] + ss[3];
    sq = sqq[0] + sqq[1] + sqq[2] + sqq[3];
    float mean = s * (1.f / DD);
    float var = sq * (1.f / DD) - mean * mean;
    float rstd = 1.f / sqrtf(var + 1e-5f);
    float o0 = (v0 - mean) * rstd * g[t] + b[t];
    float o1 = (v1 - mean) * rstd * g[t + 256] + b[t + 256];
    px[t] = o0;
    px[t + 256] = o1;
    pb[t] = f2b(o0);
    pb[t + 256] = f2b(o1);
}

// ---------------- conv helpers ----------------
__global__ void pad_copy_bf_k(const float* __restrict__ fp, ushort_t* __restrict__ fpp) {
    long total = (long)BB * TT * NW;
    for (long i = blockIdx.x * (long)blockDim.x + threadIdx.x; i < total;
         i += (long)gridDim.x * blockDim.x) {
        long ci = i % NW;
        long r = i / NW;
        long t = r % TT;
        long b = r / TT;
        fpp[(b * 130 + t + 1) * NW + ci] = f2b(fp[i]);
    }
}
__global__ void repack_bf_k(const float* __restrict__ w, ushort_t* __restrict__ wk,
                            int CO, int CI) {
    long total = (long)CO * CI * 3;
    for (long i = blockIdx.x * (long)blockDim.x + threadIdx.x; i < total;
         i += (long)gridDim.x * blockDim.x) {
        long kt = i % 3;
        long r = i / 3;
        long ci = r % CI;
        long co = r / CI;
        wk[kt * (long)CO * CI + co * CI + ci] = f2b(w[i]);
    }
}
__global__ __launch_bounds__(128) void conv5_bf_k(const ushort_t* __restrict__ h4,
                                                  const float* __restrict__ w,
                                                  const float* __restrict__ bias,
                                                  float* __restrict__ out) {
    int b = blockIdx.x, t = threadIdx.x;
    __shared__ float wsm[384];
    wsm[t] = w[t];
    wsm[t + 128] = w[t + 128];
    wsm[t + 256] = w[t + 256];
    __syncthreads();
    const ushort_t* hb = h4 + (long)b * 130 * 128;
    float acc = bias[0];
    for (int ci = 0; ci < 128; ci++) {
        float w0 = wsm[ci * 3], w1 = wsm[ci * 3 + 1], w2 = wsm[ci * 3 + 2];
        acc += w0 * b2f(hb[(t + 0) * 128 + ci]) + w1 * b2f(hb[(t + 1) * 128 + ci]) +
               w2 * b2f(hb[(t + 2) * 128 + ci]);
    }
    out[b * TT + t] = 1.f / (1.f + expf(-acc));
}

// ---------------- masked segment softmax pooling ----------------
__global__ __launch_bounds__(128) void seg_pool_k(const float* __restrict__ weights,
                                                  const int* __restrict__ steds,
                                                  const float* __restrict__ vid,
                                                  float* __restrict__ segf) {
    int b = blockIdx.y, sidx = blockIdx.x;
    int st = steds[(b * SS + sidx) * 2];
    int ed = steds[(b * SS + sidx) * 2 + 1];
    int t = threadIdx.x;
    float w = (t >= st && t <= ed) ? weights[b * TT + t] : -1e30f;
    __shared__ float red[2];
    __shared__ float aw[TT];
    int wave = t >> 6, lane = t & 63;
    float m = w;
    for (int o = 32; o > 0; o >>= 1) m = fmaxf(m, __shfl_xor(m, o, 64));
    if (lane == 0) red[wave] = m;
    __syncthreads();
    m = fmaxf(red[0], red[1]);
    float e = expf(w - m);
    float sum = e;
    for (int o = 32; o > 0; o >>= 1) sum += __shfl_xor(sum, o, 64);
    __syncthreads();
    if (lane == 0) red[wave] = sum;
    __syncthreads();
    sum = red[0] + red[1];
    aw[t] = e / sum;
    __syncthreads();
    #pragma unroll
    for (int i = 0; i < 4; i++) {
        int d = t + i * 128;
        float acc = 0.f;
        for (int tt = 0; tt < TT; tt++)
            acc += aw[tt] * vid[((long)b * TT + tt) * DD + d];
        segf[((long)b * SS + sidx) * DD + d] = acc;
    }
}

extern "C" void kernel_launch(void* const* d_in, const int* in_sizes, int n_in,
                              void* d_out, int out_size, void* d_ws, size_t ws_size,
                              hipStream_t stream) {
    const float* vid = (const float*)d_in[0];
    const float* actn_feats = (const float*)d_in[2];
    const float* actn_concepts = (const float*)d_in[3];
    const float* pos = (const float*)d_in[4];
    const float* Wq = (const float*)d_in[5];
    const float* bq = (const float*)d_in[6];
    const float* Wk = (const float*)d_in[7];
    const float* bk = (const float*)d_in[8];
    const float* Wv = (const float*)d_in[9];
    const float* bv = (const float*)d_in[10];
    const float* Wo = (const float*)d_in[11];
    const float* bo = (const float*)d_in[12];
    const float* W1 = (const float*)d_in[13];
    const float* b1 = (const float*)d_in[14];
    const float* W2 = (const float*)d_in[15];
    const float* b2 = (const float*)d_in[16];
    const float* g1 = (const float*)d_in[17];
    const float* bb1 = (const float*)d_in[18];
    const float* g2 = (const float*)d_in[19];
    const float* bb2 = (const float*)d_in[20];
    const float* pqW = (const float*)d_in[21];
    const float* pqb = (const float*)d_in[22];
    const float* pkW = (const float*)d_in[23];
    const float* pkb = (const float*)d_in[24];
    const float* pvW = (const float*)d_in[25];
    const float* pvb = (const float*)d_in[26];
    const float* c1w = (const float*)d_in[27];
    const float* c1b = (const float*)d_in[28];
    const float* c2w = (const float*)d_in[29];
    const float* c2b = (const float*)d_in[30];
    const float* c3w = (const float*)d_in[31];
    const float* c3b = (const float*)d_in[32];
    const float* c4w = (const float*)d_in[33];
    const float* c4b = (const float*)d_in[34];
    const float* c5w = (const float*)d_in[35];
    const float* c5b = (const float*)d_in[36];
    const int* steds = (const int*)d_in[37];

    float* out = (float*)d_out;
    float* fc_out = out;            // 32*128
    float* al_out = out + 4096;     // 32*8*200
    float* fp_out = out + 55296;    // 32*128*2000

    float* ws = (float*)d_ws;
    const long NEED = 25165824;  // floats (96 MiB) — proven available
    if (ws_size < (size_t)NEED * 4) {
        sentinel_k<<<1, 1, 0, stream>>>(fc_out);
        return;
    }

    // ---- arena (float-unit offsets) ----
    // phase A:
    const long A_XBF   = 0;          // x bf16 (1,048,576)
    const long A_QKVBF = 1048576;    // qkv bf16 (3,145,728) -> 4,194,304
    const long A_VT    = 4194304;    // vT bf16 (1,048,576) -> 5,242,880
    const long A_FFH   = 7340032;    // ffh bf16 (4,194,304) -> 11,534,336
    const long A_AOBF  = 11534336;   // attn out bf16 (1,048,576) -> 12,582,912
    const long A_QB    = 12582912;   // fp32 scratch (2,097,152) -> 14,680,064
    const long A_QKVT  = 14680064;   // -> 16,252,928
    const long A_WOT   = 16252928;   // -> 16,777,216
    const long A_W1T   = 16777216;   // -> 18,874,368
    const long A_W2T   = 18874368;   // -> 20,971,520
    const long A_QKVB  = 20971520;   // -> 20,977,664
    const long XB      = 21000192;   // x fp32 -> 23,097,344
    // phase B (xbf..phase-A stuff dead; xb read once then dead):
    const long B_UPD   = 0;          // upd bf16 full (16,384,000) -> 16,384,000
    const long B_VPRBF = 16384000;   // vproj bf16 (1,048,576) -> 17,432,576
    const long B_PW    = 17432576;   // pq/pk/pvT (393,216) -> 17,825,792
    const long B_ACBF  = 17825792;   // concepts bf16 (512,000) -> 18,337,792
    const long B_QPBF  = 18337792;   // Qp bf16 (512,000) -> 18,849,792
    const long B_KPBF  = 18849792;   // Kp bf16 (1,048,576) -> 19,898,368
    const long B_VP    = 19898368;   // Vp fp32 (2,097,152) -> 21,995,520 (after xb read)
    const long B_VPT   = 21995520;   // VpT bf16 (1,048,576) -> 23,044,096
    // phase C (phase-B stuff dead after feats_proj):
    const long C_FPP   = 0;
    const long C_WK1   = 4160000;
    const long C_WK2   = 7232000;
    const long C_WK3   = 8018432;
    const long C_WK4   = 8215040;
    const long C_H1    = 8264192;
    const long C_H2    = 10394112;
    const long C_H3    = 11459072;
    const long C_H4    = 11991552;
    const long C_SEGF  = 12257792;   // -> 12,388,864
    const long ZPAD    = 25165760;   // zbuf (64 floats), never overwritten

    float* xb = ws + XB;
    const ushort_t* zbuf = (const ushort_t*)(ws + ZPAD);
    const long nBTD = (long)BB * TT * DD;

    zero_k<<<1, 64, 0, stream>>>(ws + ZPAD, 64);

    ushort_t* xbf = (ushort_t*)(ws + A_XBF);
    addpos_bf_k<<<2048, 256, 0, stream>>>(vid, pos, xb, xbf, nBTD, (long)TT * DD);

    // ---- all-layer weight prep ----
    ushort_t* qkvT = (ushort_t*)(ws + A_QKVT);
    ushort_t* WoT  = (ushort_t*)(ws + A_WOT);
    ushort_t* W1T  = (ushort_t*)(ws + A_W1T);
    ushort_t* W2T  = (ushort_t*)(ws + A_W2T);
    float*    qkvb = ws + A_QKVB;
    dim3 tblk(32, 8);
    f2b_t_k<<<dim3(16, 16, LL), tblk, 0, stream>>>(Wq, qkvT, DD, DD, (long)DD * DD, 786432);
    f2b_t_k<<<dim3(16, 16, LL), tblk, 0, stream>>>(Wk, qkvT + 262144, DD, DD, (long)DD * DD, 786432);
    f2b_t_k<<<dim3(16, 16, LL), tblk, 0, stream>>>(Wv, qkvT + 524288, DD, DD, (long)DD * DD, 786432);
    f2b_t_k<<<dim3(16, 16, LL), tblk, 0, stream>>>(Wo, WoT, DD, DD, (long)DD * DD, 262144);
    f2b_t_k<<<dim3(64, 16, LL), tblk, 0, stream>>>(W1, W1T, DD, FF, (long)DD * FF, 1048576);
    f2b_t_k<<<dim3(16, 64, LL), tblk, 0, stream>>>(W2, W2T, FF, DD, (long)FF * DD, 1048576);
    cat3all_k<<<(LL * 1536 + 255) / 256, 256, 0, stream>>>(qkvb, bq, bk, bv);

    // ================= phase A: transformer =================
    ushort_t* qkvbf = (ushort_t*)(ws + A_QKVBF);
    ushort_t* vTb   = (ushort_t*)(ws + A_VT);
    ushort_t* ffhbf = (ushort_t*)(ws + A_FFH);
    ushort_t* aobf  = (ushort_t*)(ws + A_AOBF);
    float*    qb    = ws + A_QB;

    for (int l = 0; l < LL; l++) {
        launch_bgemm(0, 1, xbf, DD, 0, 0, qkvT + (long)l * 786432, DD, 0, 0,
                     qkvbf, 1536, 0, 0, qkvb + (long)l * 1536,
                     BB * TT, 1536, DD, 1.f, 1, 1, 1, 0, 0, zbuf, stream);
        t_bf_k<<<dim3(16, 4, BB), tblk, 0, stream>>>(qkvbf + 1024, vTb, TT, DD, 1536,
                                                     (long)TT * 1536, (long)DD * TT);
        // fused attention: QK^T/8 -> softmax -> PV
        fattn_k<0><<<BB * HH, 256, 0, stream>>>(
            qkvbf, 1536, (long)TT * 1536, 0,
            qkvbf + 512, 1536, (long)TT * 1536,
            vTb, (long)DD * TT,
            aobf, DD, (long)TT * DD, 0, 1, TT, zbuf);
        launch_bgemm(0, 0, aobf, DD, 0, 0, WoT + (long)l * 262144, DD, 0, 0,
                     qb, DD, 0, 0, bo + (long)l * DD,
                     BB * TT, DD, DD, 1.f, 1, 1, 1, 0, 0, zbuf, stream);
        ln_res_k<<<BB * TT, 256, 0, stream>>>(xb, qb, xbf, g1 + (long)l * DD, bb1 + (long)l * DD);
        launch_bgemm(1, 1, xbf, DD, 0, 0, W1T + (long)l * 1048576, DD, 0, 0,
                     ffhbf, FF, 0, 0, b1 + (long)l * FF,
                     BB * TT, FF, DD, 1.f, 1, 1, 1, 0, 0, zbuf, stream);
        launch_bgemm(0, 0, ffhbf, FF, 0, 0, W2T + (long)l * 1048576, FF, 0, 0,
                     qb, DD, 0, 0, b2 + (long)l * DD,
                     BB * TT, DD, FF, 1.f, 1, 1, 1, 0, 0, zbuf, stream);
        ln_res_k<<<BB * TT, 256, 0, stream>>>(xb, qb, xbf, g2 + (long)l * DD, bb2 + (long)l * DD);
    }

    // ================= phase B: cross-attn + feats_proj =================
    ushort_t* updbf = (ushort_t*)(ws + B_UPD);
    ushort_t* vprbf = (ushort_t*)(ws + B_VPRBF);
    ushort_t* pqT   = (ushort_t*)(ws + B_PW);
    ushort_t* pkT   = (ushort_t*)(ws + B_PW + 131072);
    ushort_t* pvT   = (ushort_t*)(ws + B_PW + 262144);
    ushort_t* acbf  = (ushort_t*)(ws + B_ACBF);
    ushort_t* Qpbf  = (ushort_t*)(ws + B_QPBF);
    ushort_t* Kpbf  = (ushort_t*)(ws + B_KPBF);
    float*    Vp    = ws + B_VP;
    ushort_t* VpT   = (ushort_t*)(ws + B_VPT);

    add_f2b_k<<<1024, 256, 0, stream>>>(vid, xb, vprbf, nBTD);   // xb dead after this
    f2b_t_k<<<dim3(16, 16, 1), tblk, 0, stream>>>(pqW, pqT, DD, DD, 0, 0);
    f2b_t_k<<<dim3(16, 16, 1), tblk, 0, stream>>>(pkW, pkT, DD, DD, 0, 0);
    f2b_t_k<<<dim3(16, 16, 1), tblk, 0, stream>>>(pvW, pvT, DD, DD, 0, 0);
    f2b_k<<<512, 256, 0, stream>>>(actn_concepts, acbf, (long)NW * DD);

    launch_bgemm(0, 1, acbf, DD, 0, 0, pqT, DD, 0, 0, Qpbf, DD, 0, 0,
                 pqb, NW, DD, DD, 1.f, 1, 1, 1, 0, 0, zbuf, stream);
    launch_bgemm(0, 1, vprbf, DD, 0, 0, pkT, DD, 0, 0, Kpbf, DD, 0, 0,
                 pkb, BB * TT, DD, DD, 1.f, 1, 1, 1, 0, 0, zbuf, stream);
    launch_bgemm(0, 0, vprbf, DD, 0, 0, pvT, DD, 0, 0, Vp, DD, 0, 0,
                 pvb, BB * TT, DD, DD, 1.f, 1, 1, 1, 0, 0, zbuf, stream);
    f2b_t_k<<<dim3(16, 4, BB), tblk, 0, stream>>>(Vp, VpT, TT, DD, (long)TT * DD, (long)TT * DD);

    // fused cross-attention: one launch, 16 concept-chunks of 128
    fattn_k<1><<<BB * HH * 16, 256, 0, stream>>>(
        Qpbf, DD, 0, (long)128 * DD,
        Kpbf, DD, (long)TT * DD,
        VpT, (long)DD * TT,
        updbf, DD, (long)NW * DD, (long)128 * DD, 16, NW, zbuf);

    // feats_proj: fp[b,t,n] = vproj[b,t,:] . upd[b,n,:]
    launch_bgemm(0, 0, vprbf, DD, (long)TT * DD, 0,
                 updbf, DD, (long)NW * DD, 0,
                 fp_out, NW, (long)TT * NW, 0,
                 nullptr, TT, NW, DD, 1.f, 1, BB, 1, 0, 0, zbuf, stream);

    // ================= phase C: conv tower (merged-M, taps as row shifts) ===
    ushort_t* fpp = (ushort_t*)(ws + C_FPP);
    ushort_t* wk1 = (ushort_t*)(ws + C_WK1);
    ushort_t* wk2 = (ushort_t*)(ws + C_WK2);
    ushort_t* wk3 = (ushort_t*)(ws + C_WK3);
    ushort_t* wk4 = (ushort_t*)(ws + C_WK4);
    ushort_t* h1  = (ushort_t*)(ws + C_H1);
    ushort_t* h2  = (ushort_t*)(ws + C_H2);
    ushort_t* h3  = (ushort_t*)(ws + C_H3);
    ushort_t* h4  = (ushort_t*)(ws + C_H4);

    repack_bf_k<<<1024, 256, 0, stream>>>(c1w, wk1, 1024, NW);
    repack_bf_k<<<512, 256, 0, stream>>>(c2w, wk2, 512, 1024);
    repack_bf_k<<<256, 256, 0, stream>>>(c3w, wk3, 256, 512);
    repack_bf_k<<<128, 256, 0, stream>>>(c4w, wk4, 128, 256);
    padzero_k<<<BB, 256, 0, stream>>>(fpp, NW);
    pad_copy_bf_k<<<2048, 256, 0, stream>>>(fp_out, fpp);

    const int MROWS = BB * 130 - 2;  // 4158: out row gm -> padded row gm+1
    launch_bgemm(1, 1, fpp, NW, 0, 0, wk1, NW, 0, 0,
                 h1 + 1024, 1024, 0, 0, c1b,
                 MROWS, 1024, NW, 1.f, 1, 1, 3, NW, (long)1024 * NW, zbuf, stream);
    padzero_k<<<BB, 256, 0, stream>>>(h1, 1024);
    launch_bgemm(1, 1, h1, 1024, 0, 0, wk2, 1024, 0, 0,
                 h2 + 512, 512, 0, 0, c2b,
                 MROWS, 512, 1024, 1.f, 1, 1, 3, 1024, (long)512 * 1024, zbuf, stream);
    padzero_k<<<BB, 256, 0, stream>>>(h2, 512);
    launch_bgemm(1, 1, h2, 512, 0, 0, wk3, 512, 0, 0,
                 h3 + 256, 256, 0, 0, c3b,
                 MROWS, 256, 512, 1.f, 1, 1, 3, 512, (long)256 * 512, zbuf, stream);
    padzero_k<<<BB, 256, 0, stream>>>(h3, 256);
    launch_bgemm(1, 1, h3, 256, 0, 0, wk4, 256, 0, 0,
                 h4 + 128, 128, 0, 0, c4b,
                 MROWS, 128, 256, 1.f, 1, 1, 3, 256, (long)128 * 256, zbuf, stream);
    padzero_k<<<BB, 256, 0, stream>>>(h4, 128);
    conv5_bf_k<<<BB, 128, 0, stream>>>(h4, c5w, c5b, fc_out);

    // ================= segment pooling + logits (fp32) =================
    float* segf = ws + C_SEGF;
    seg_pool_k<<<dim3(SS, BB), 128, 0, stream>>>(fc_out, steds, vid, segf);
    gemm_k<1><<<dim3((NCC + 63) / 64, (BB * SS + 63) / 64, 1), 256, 0, stream>>>(
        segf, DD, actn_feats, DD, al_out, NCC, BB * SS, NCC, DD);
}